// Round 1
// baseline (696.408 us; speedup 1.0000x reference)
//
#include <hip/hip_runtime.h>
#include <stdint.h>

#define DIM 384
#define INNER 1536
#define H2X 3072
#define NE 5
#define NB 4
#define NT 1024
#define NN (NB*NT)
#define KSZ 31
#define SQZ 48
#define NASSIGN (NN*2)

typedef float floatx4 __attribute__((ext_vector_type(4)));
typedef __bf16 bf16x8 __attribute__((ext_vector_type(8)));

__device__ __forceinline__ unsigned short f2bs(float f){
  union { float f; uint32_t u; } v; v.f = f;
  uint32_t r = (v.u + 0x7fffu + ((v.u >> 16) & 1u)) >> 16;
  return (unsigned short)r;
}
__device__ __forceinline__ float bs2f(unsigned short s){
  union { uint32_t u; float f; } v; v.u = ((uint32_t)s) << 16; return v.f;
}
__device__ __forceinline__ float fsigmoid(float x){ return 1.f/(1.f+__expf(-x)); }

// ---------------- transpose + cast f32 [z][R][C] -> bf16 [z][C][R] ----------------
__global__ __launch_bounds__(256) void transpose_cast_kernel(const float* __restrict__ in,
    unsigned short* __restrict__ out, int R, int C){
  __shared__ float tile[32][33];
  int z = blockIdx.z;
  in  += (size_t)z * R * C;
  out += (size_t)z * R * C;
  int c0 = blockIdx.x*32, r0 = blockIdx.y*32;
  int tx = threadIdx.x, ty = threadIdx.y;
  #pragma unroll
  for (int i=0;i<4;i++){
    int r = r0 + ty + i*8;
    tile[ty+i*8][tx] = in[(size_t)r*C + c0 + tx];
  }
  __syncthreads();
  #pragma unroll
  for (int i=0;i<4;i++){
    int c = c0 + ty + i*8;
    out[(size_t)c*R + r0 + tx] = f2bs(tile[tx][ty+i*8]);
  }
}

// ---------------- LayerNorm: res -> x ----------------
__global__ __launch_bounds__(128) void ln_kernel(const float* __restrict__ res,
    const float* __restrict__ g, const float* __restrict__ b, float* __restrict__ x){
  int row = blockIdx.x; int tid = threadIdx.x;
  const float* r = res + (size_t)row*DIM;
  float v0=r[tid], v1=r[tid+128], v2=r[tid+256];
  float s = v0+v1+v2;
  #pragma unroll
  for(int o=32;o;o>>=1) s += __shfl_down(s,o);
  __shared__ float sb[2];
  int lane = tid&63, w = tid>>6;
  if(lane==0) sb[w]=s;
  __syncthreads();
  float mean = (sb[0]+sb[1]) * (1.f/DIM);
  __syncthreads();
  float d0=v0-mean,d1=v1-mean,d2=v2-mean;
  float q = d0*d0+d1*d1+d2*d2;
  #pragma unroll
  for(int o=32;o;o>>=1) q += __shfl_down(q,o);
  if(lane==0) sb[w]=q;
  __syncthreads();
  float rstd = rsqrtf((sb[0]+sb[1])*(1.f/DIM) + 1e-5f);
  float* xo = x + (size_t)row*DIM;
  xo[tid]     = d0*rstd*g[tid]     + b[tid];
  xo[tid+128] = d1*rstd*g[tid+128] + b[tid+128];
  xo[tid+256] = d2*rstd*g[tid+256] + b[tid+256];
}

// ---------------- depthwise conv over time: x -> h (f32), tok_bf16, y=h ----------------
#define CTT 8
__global__ __launch_bounds__(384) void conv_kernel(const float* __restrict__ x,
    const float* __restrict__ cw, const float* __restrict__ cb,
    float* __restrict__ h, unsigned short* __restrict__ tokb, float* __restrict__ y){
  __shared__ float tile[(CTT+30)*DIM];
  int b = blockIdx.y, t0 = blockIdx.x*CTT;
  int tid = threadIdx.x;
  for (int r=0;r<CTT+30;r++){
    int gt = t0 - 15 + r;
    float v = (gt>=0 && gt<NT) ? x[((size_t)b*NT+gt)*DIM + tid] : 0.f;
    tile[r*DIM+tid] = v;
  }
  __syncthreads();
  float w[KSZ];
  #pragma unroll
  for(int k=0;k<KSZ;k++) w[k] = cw[tid*KSZ+k];
  float bias = cb[tid];
  for(int t=0;t<CTT;t++){
    float acc = bias;
    #pragma unroll
    for(int k=0;k<KSZ;k++) acc += tile[(t+k)*DIM+tid]*w[k];
    size_t o = ((size_t)b*NT + t0 + t)*DIM + tid;
    h[o]=acc; y[o]=acc; tokb[o]=f2bs(acc);
  }
}

// ---------------- router GEMM1: g1 = silu(tok @ rw1 + rb1), bf16 out ----------------
__global__ __launch_bounds__(256) void router_g1_kernel(const unsigned short* __restrict__ tokb,
    const unsigned short* __restrict__ rw1t, const float* __restrict__ rb1,
    unsigned short* __restrict__ g1){
  __shared__ alignas(16) unsigned short sA[128*32];
  __shared__ alignas(16) unsigned short sB[128*32];
  int tid = threadIdx.x;
  int n0 = blockIdx.x*128, m0 = blockIdx.y*128;
  int lane = tid&63, wid = tid>>6, wm = wid&1, wn = wid>>1;
  int l15 = lane&15, quad = lane>>4;
  floatx4 acc[4][4];
  #pragma unroll
  for(int i=0;i<4;i++)
    #pragma unroll
    for(int j=0;j<4;j++) acc[i][j]=(floatx4){0.f,0.f,0.f,0.f};
  int rA = tid>>2, c8 = tid&3;
  for(int kt=0; kt<DIM; kt+=32){
    uint4 a0 = *(const uint4*)&tokb[(size_t)(m0+rA)*DIM + kt + c8*8];
    uint4 a1 = *(const uint4*)&tokb[(size_t)(m0+64+rA)*DIM + kt + c8*8];
    uint4 b0 = *(const uint4*)&rw1t[(size_t)(n0+rA)*DIM + kt + c8*8];
    uint4 b1 = *(const uint4*)&rw1t[(size_t)(n0+64+rA)*DIM + kt + c8*8];
    __syncthreads();
    *(uint4*)&sA[rA*32 + c8*8] = a0;
    *(uint4*)&sA[(rA+64)*32 + c8*8] = a1;
    *(uint4*)&sB[rA*32 + c8*8] = b0;
    *(uint4*)&sB[(rA+64)*32 + c8*8] = b1;
    __syncthreads();
    bf16x8 af[4], bfr[4];
    #pragma unroll
    for(int mi=0;mi<4;mi++) af[mi] = *(const bf16x8*)&sA[(wm*64+mi*16+l15)*32 + quad*8];
    #pragma unroll
    for(int ni=0;ni<4;ni++) bfr[ni] = *(const bf16x8*)&sB[(wn*64+ni*16+l15)*32 + quad*8];
    #pragma unroll
    for(int mi=0;mi<4;mi++)
      #pragma unroll
      for(int ni=0;ni<4;ni++)
        acc[mi][ni] = __builtin_amdgcn_mfma_f32_16x16x32_bf16(af[mi], bfr[ni], acc[mi][ni],0,0,0);
  }
  #pragma unroll
  for(int ni=0;ni<4;ni++){
    int col = n0 + wn*64 + ni*16 + l15;
    float bias = rb1[col];
    #pragma unroll
    for(int mi=0;mi<4;mi++){
      int rowb = m0 + wm*64 + mi*16 + quad*4;
      #pragma unroll
      for(int r=0;r<4;r++){
        float v = acc[mi][ni][r] + bias;
        g1[(size_t)(rowb+r)*DIM + col] = f2bs(v*fsigmoid(v));
      }
    }
  }
}

// ---------------- router2: scores, top2, softmax, counts ----------------
__global__ __launch_bounds__(256) void router2_kernel(const unsigned short* __restrict__ g1,
    const float* __restrict__ rw2, const float* __restrict__ rb2,
    int* __restrict__ ridx, float* __restrict__ rwt, int* __restrict__ cnt){
  int wid = threadIdx.x>>6, lane = threadIdx.x&63;
  int n = blockIdx.x*4 + wid;
  float s[NE]={0.f,0.f,0.f,0.f,0.f};
  #pragma unroll
  for(int i=0;i<6;i++){
    int d = lane + i*64;
    float gv = bs2f(g1[(size_t)n*DIM+d]);
    #pragma unroll
    for(int e=0;e<NE;e++) s[e] += gv * rw2[d*NE+e];
  }
  #pragma unroll
  for(int e=0;e<NE;e++)
    #pragma unroll
    for(int o=32;o;o>>=1) s[e] += __shfl_down(s[e],o);
  if(lane==0){
    float r[NE];
    #pragma unroll
    for(int e=0;e<NE;e++) r[e]=s[e]+rb2[e];
    int e0=0;
    for(int e=1;e<NE;e++) if(r[e]>r[e0]) e0=e;
    int e1=-1;
    for(int e=0;e<NE;e++){ if(e==e0) continue; if(e1<0||r[e]>r[e1]) e1=e; }
    float w0 = 1.f/(1.f+__expf(r[e1]-r[e0]));
    ridx[2*n]=e0; ridx[2*n+1]=e1;
    rwt[2*n]=w0; rwt[2*n+1]=1.f-w0;
    atomicAdd(&cnt[e0],1); atomicAdd(&cnt[e1],1);
  }
}

__global__ void prefix_kernel(const int* __restrict__ cnt, int* __restrict__ poff, int* __restrict__ cursor){
  if(threadIdx.x==0 && blockIdx.x==0){
    int run=0;
    for(int e=0;e<NE;e++){ poff[e]=run; cursor[e]=run; run+=cnt[e]; }
  }
}

__global__ __launch_bounds__(256) void fill_kernel(const int* __restrict__ ridx,
    const float* __restrict__ rwt, int* __restrict__ cursor,
    int* __restrict__ perm, float* __restrict__ pw){
  int i = blockIdx.x*256 + threadIdx.x;
  int e = ridx[i];
  int pos = atomicAdd(&cursor[e],1);
  perm[pos] = i>>1;
  pw[pos] = rwt[i];
}

// ---------------- expert GEMM with fused SwiGLU ----------------
template<int KDIM, bool GATHER>
__global__ __launch_bounds__(256) void gemm_swiglu_kernel(
    const unsigned short* __restrict__ A, const int* __restrict__ perm,
    const unsigned short* __restrict__ wt, const float* __restrict__ bias,
    const int* __restrict__ cnt, const int* __restrict__ poff,
    unsigned short* __restrict__ out){
  int e = blockIdx.z;
  int cn = cnt[e];
  int mtile = blockIdx.y;
  if (mtile*128 >= cn) return;
  int base = poff[e];
  int j0 = blockIdx.x*64;
  int tid=threadIdx.x, lane=tid&63, wid=tid>>6, wm=wid&1, wn=wid>>1;
  int l15=lane&15, quad=lane>>4;
  __shared__ alignas(16) unsigned short sA[128*32];
  __shared__ alignas(16) unsigned short sBa[64*32];
  __shared__ alignas(16) unsigned short sBg[64*32];
  int rA = tid>>2, c8 = tid&3;
  int lr0 = mtile*128 + rA, lr1 = lr0+64;
  int p0 = base + min(lr0, cn-1);
  int p1 = base + min(lr1, cn-1);
  const unsigned short *a0p, *a1p;
  if constexpr (GATHER){
    a0p = A + (size_t)perm[p0]*KDIM;
    a1p = A + (size_t)perm[p1]*KDIM;
  } else {
    a0p = A + (size_t)p0*KDIM;
    a1p = A + (size_t)p1*KDIM;
  }
  const unsigned short* bap = wt + ((size_t)e*H2X + j0 + rA)*KDIM;
  const unsigned short* bgp = wt + ((size_t)e*H2X + INNER + j0 + rA)*KDIM;
  floatx4 aca[4][2], acg[4][2];
  #pragma unroll
  for(int i=0;i<4;i++)
    #pragma unroll
    for(int j=0;j<2;j++){ aca[i][j]=(floatx4){0.f,0.f,0.f,0.f}; acg[i][j]=(floatx4){0.f,0.f,0.f,0.f}; }
  for(int kt=0; kt<KDIM; kt+=32){
    uint4 a0 = *(const uint4*)&a0p[kt + c8*8];
    uint4 a1 = *(const uint4*)&a1p[kt + c8*8];
    uint4 b0 = *(const uint4*)&bap[kt + c8*8];
    uint4 b1 = *(const uint4*)&bgp[kt + c8*8];
    __syncthreads();
    *(uint4*)&sA[rA*32 + c8*8] = a0;
    *(uint4*)&sA[(rA+64)*32 + c8*8] = a1;
    *(uint4*)&sBa[rA*32 + c8*8] = b0;
    *(uint4*)&sBg[rA*32 + c8*8] = b1;
    __syncthreads();
    bf16x8 af[4], ba[2], bg[2];
    #pragma unroll
    for(int mi=0;mi<4;mi++) af[mi] = *(const bf16x8*)&sA[(wm*64+mi*16+l15)*32 + quad*8];
    #pragma unroll
    for(int ni=0;ni<2;ni++){
      ba[ni] = *(const bf16x8*)&sBa[(wn*32+ni*16+l15)*32 + quad*8];
      bg[ni] = *(const bf16x8*)&sBg[(wn*32+ni*16+l15)*32 + quad*8];
    }
    #pragma unroll
    for(int mi=0;mi<4;mi++)
      #pragma unroll
      for(int ni=0;ni<2;ni++){
        aca[mi][ni] = __builtin_amdgcn_mfma_f32_16x16x32_bf16(af[mi], ba[ni], aca[mi][ni],0,0,0);
        acg[mi][ni] = __builtin_amdgcn_mfma_f32_16x16x32_bf16(af[mi], bg[ni], acg[mi][ni],0,0,0);
      }
  }
  #pragma unroll
  for(int ni=0;ni<2;ni++){
    int j = j0 + wn*32 + ni*16 + l15;
    float ba_ = bias[e*H2X + j];
    float bg_ = bias[e*H2X + INNER + j];
    #pragma unroll
    for(int mi=0;mi<4;mi++){
      int rl = wm*64 + mi*16 + quad*4;
      #pragma unroll
      for(int r=0;r<4;r++){
        int row = mtile*128 + rl + r;
        if(row < cn){
          float a = aca[mi][ni][r] + ba_;
          float g = acg[mi][ni][r] + bg_;
          out[(size_t)(base+row)*INNER + j] = f2bs(a * g * fsigmoid(g));
        }
      }
    }
  }
}

// ---------------- expert output GEMM + weighted scatter into y ----------------
__global__ __launch_bounds__(256) void gemm_out_kernel(
    const unsigned short* __restrict__ h2, const unsigned short* __restrict__ w3t,
    const float* __restrict__ be3, const int* __restrict__ cnt, const int* __restrict__ poff,
    const int* __restrict__ perm, const float* __restrict__ pw, float* __restrict__ y){
  int e = blockIdx.z;
  int cn = cnt[e];
  int mtile = blockIdx.y;
  if (mtile*128 >= cn) return;
  int base = poff[e];
  int n0 = blockIdx.x*128;
  int tid=threadIdx.x, lane=tid&63, wid=tid>>6, wm=wid&1, wn=wid>>1;
  int l15=lane&15, quad=lane>>4;
  __shared__ alignas(16) unsigned short sA[128*32];
  __shared__ alignas(16) unsigned short sB[128*32];
  int rA = tid>>2, c8 = tid&3;
  int lr0 = mtile*128 + rA, lr1 = lr0+64;
  const unsigned short* a0p = h2 + (size_t)(base + min(lr0, cn-1))*INNER;
  const unsigned short* a1p = h2 + (size_t)(base + min(lr1, cn-1))*INNER;
  const unsigned short* b0p = w3t + ((size_t)e*DIM + n0 + rA)*INNER;
  const unsigned short* b1p = w3t + ((size_t)e*DIM + n0 + 64 + rA)*INNER;
  floatx4 acc[4][4];
  #pragma unroll
  for(int i=0;i<4;i++)
    #pragma unroll
    for(int j=0;j<4;j++) acc[i][j]=(floatx4){0.f,0.f,0.f,0.f};
  for(int kt=0; kt<INNER; kt+=32){
    uint4 a0 = *(const uint4*)&a0p[kt + c8*8];
    uint4 a1 = *(const uint4*)&a1p[kt + c8*8];
    uint4 b0 = *(const uint4*)&b0p[kt + c8*8];
    uint4 b1 = *(const uint4*)&b1p[kt + c8*8];
    __syncthreads();
    *(uint4*)&sA[rA*32 + c8*8] = a0;
    *(uint4*)&sA[(rA+64)*32 + c8*8] = a1;
    *(uint4*)&sB[rA*32 + c8*8] = b0;
    *(uint4*)&sB[(rA+64)*32 + c8*8] = b1;
    __syncthreads();
    bf16x8 af[4], bfr[4];
    #pragma unroll
    for(int mi=0;mi<4;mi++) af[mi] = *(const bf16x8*)&sA[(wm*64+mi*16+l15)*32 + quad*8];
    #pragma unroll
    for(int ni=0;ni<4;ni++) bfr[ni] = *(const bf16x8*)&sB[(wn*64+ni*16+l15)*32 + quad*8];
    #pragma unroll
    for(int mi=0;mi<4;mi++)
      #pragma unroll
      for(int ni=0;ni<4;ni++)
        acc[mi][ni] = __builtin_amdgcn_mfma_f32_16x16x32_bf16(af[mi], bfr[ni], acc[mi][ni],0,0,0);
  }
  #pragma unroll
  for(int ni=0;ni<4;ni++){
    int col = n0 + wn*64 + ni*16 + l15;
    float b3 = be3[e*DIM + col];
    #pragma unroll
    for(int mi=0;mi<4;mi++){
      int rl = wm*64 + mi*16 + quad*4;
      #pragma unroll
      for(int r=0;r<4;r++){
        int row = mtile*128 + rl + r;
        if(row < cn){
          int pos = base + row;
          float wv = pw[pos];
          int tokn = perm[pos];
          atomicAdd(&y[(size_t)tokn*DIM + col], wv*(acc[mi][ni][r] + b3));
        }
      }
    }
  }
}

// ---------------- senet pooled / gate / final ----------------
__global__ __launch_bounds__(384) void pooled_kernel(const float* __restrict__ x,
    const float* __restrict__ sres, const float* __restrict__ y, float* __restrict__ pooled){
  int b = blockIdx.x>>3, c = blockIdx.x&7;
  int d = threadIdx.x;
  float sr = sres[d];
  float s=0.f;
  for(int t=c*128;t<c*128+128;t++){
    size_t o=((size_t)b*NT+t)*DIM+d;
    s += x[o]*sr + y[o];
  }
  atomicAdd(&pooled[b*DIM+d], s*(1.f/NT));
}

__global__ __launch_bounds__(128) void gate_kernel(const float* __restrict__ pooled,
    const float* __restrict__ sw1, const float* __restrict__ sb1,
    const float* __restrict__ sw2, const float* __restrict__ sb2, float* __restrict__ gate){
  int b=blockIdx.x; int tid=threadIdx.x;
  __shared__ float sp[DIM];
  __shared__ float sh[SQZ];
  for(int i=tid;i<DIM;i+=128) sp[i]=pooled[b*DIM+i];
  __syncthreads();
  if(tid<SQZ){
    float a=sb1[tid];
    for(int d=0;d<DIM;d++) a += sp[d]*sw1[d*SQZ+tid];
    sh[tid]= a*fsigmoid(a);
  }
  __syncthreads();
  for(int i=tid;i<DIM;i+=128){
    float a=sb2[i];
    #pragma unroll
    for(int j=0;j<SQZ;j++) a += sh[j]*sw2[j*DIM+i];
    gate[b*DIM+i]=fsigmoid(a);
  }
}

__global__ __launch_bounds__(256) void final_kernel(const float* __restrict__ res,
    const float* __restrict__ y, const float* __restrict__ gate, float* __restrict__ out){
  int i4 = blockIdx.x*256+threadIdx.x;
  int d4 = i4 % 96; int row = i4 / 96; int b = row>>10;
  float4 r = *(const float4*)&res[(size_t)i4*4];
  float4 yv = *(const float4*)&y[(size_t)i4*4];
  float4 gv = *(const float4*)&gate[b*DIM + d4*4];
  float4 o;
  o.x=r.x+yv.x*gv.x; o.y=r.y+yv.y*gv.y; o.z=r.z+yv.z*gv.z; o.w=r.w+yv.w*gv.w;
  *(float4*)&out[(size_t)i4*4]=o;
}

extern "C" void kernel_launch(void* const* d_in, const int* in_sizes, int n_in,
                              void* d_out, int out_size, void* d_ws, size_t ws_size,
                              hipStream_t stream) {
  (void)in_sizes; (void)n_in; (void)out_size; (void)ws_size;
  const float* res   = (const float*)d_in[0];
  const float* ln_g  = (const float*)d_in[1];
  const float* ln_b  = (const float*)d_in[2];
  const float* conv_w= (const float*)d_in[3];
  const float* conv_b= (const float*)d_in[4];
  const float* rw1   = (const float*)d_in[5];
  const float* rb1   = (const float*)d_in[6];
  const float* rw2   = (const float*)d_in[7];
  const float* rb2   = (const float*)d_in[8];
  const float* we1   = (const float*)d_in[9];
  const float* be1   = (const float*)d_in[10];
  const float* we2   = (const float*)d_in[11];
  const float* be2   = (const float*)d_in[12];
  const float* we3   = (const float*)d_in[13];
  const float* be3   = (const float*)d_in[14];
  const float* sw1   = (const float*)d_in[15];
  const float* sb1   = (const float*)d_in[16];
  const float* sw2   = (const float*)d_in[17];
  const float* sb2   = (const float*)d_in[18];
  const float* sres  = (const float*)d_in[19];
  float* out = (float*)d_out;

  char* ws = (char*)d_ws;
  size_t off = 0;
  auto alloc = [&](size_t bytes)->void*{ void* p = ws + off; off = (off + bytes + 255) & ~(size_t)255; return p; };
  float*          x     = (float*)alloc((size_t)NN*DIM*4);
  float*          h     = (float*)alloc((size_t)NN*DIM*4);
  float*          y     = (float*)alloc((size_t)NN*DIM*4);
  unsigned short* tokb  = (unsigned short*)alloc((size_t)NN*DIM*2);
  unsigned short* g1    = (unsigned short*)alloc((size_t)NN*DIM*2);
  unsigned short* w1t   = (unsigned short*)alloc((size_t)NE*H2X*DIM*2);
  unsigned short* w2t   = (unsigned short*)alloc((size_t)NE*H2X*INNER*2);
  unsigned short* w3t   = (unsigned short*)alloc((size_t)NE*DIM*INNER*2);
  unsigned short* rw1t  = (unsigned short*)alloc((size_t)DIM*DIM*2);
  unsigned short* h1    = (unsigned short*)alloc((size_t)NASSIGN*INNER*2);
  unsigned short* h2b   = (unsigned short*)alloc((size_t)NASSIGN*INNER*2);
  int*            ridx  = (int*)alloc((size_t)NASSIGN*4);
  float*          rwt   = (float*)alloc((size_t)NASSIGN*4);
  int*            perm  = (int*)alloc((size_t)NASSIGN*4);
  float*          pw    = (float*)alloc((size_t)NASSIGN*4);
  int*            cnt   = (int*)alloc(64);
  int*            poff  = (int*)alloc(64);
  int*            cursor= (int*)alloc(64);
  float*          pooled= (float*)alloc((size_t)NB*DIM*4);
  float*          gate  = (float*)alloc((size_t)NB*DIM*4);

  dim3 tb(32,8);
  transpose_cast_kernel<<<dim3(H2X/32, DIM/32, NE), tb, 0, stream>>>(we1, w1t, DIM, H2X);
  transpose_cast_kernel<<<dim3(H2X/32, INNER/32, NE), tb, 0, stream>>>(we2, w2t, INNER, H2X);
  transpose_cast_kernel<<<dim3(DIM/32, INNER/32, NE), tb, 0, stream>>>(we3, w3t, INNER, DIM);
  transpose_cast_kernel<<<dim3(DIM/32, DIM/32, 1), tb, 0, stream>>>(rw1, rw1t, DIM, DIM);

  ln_kernel<<<NN, 128, 0, stream>>>(res, ln_g, ln_b, x);
  conv_kernel<<<dim3(NT/CTT, NB), 384, 0, stream>>>(x, conv_w, conv_b, h, tokb, y);

  hipMemsetAsync(cnt, 0, 64, stream);
  router_g1_kernel<<<dim3(DIM/128, NN/128), 256, 0, stream>>>(tokb, rw1t, rb1, g1);
  router2_kernel<<<NN/4, 256, 0, stream>>>(g1, rw2, rb2, ridx, rwt, cnt);
  prefix_kernel<<<1, 64, 0, stream>>>(cnt, poff, cursor);
  fill_kernel<<<NASSIGN/256, 256, 0, stream>>>(ridx, rwt, cursor, perm, pw);

  gemm_swiglu_kernel<DIM, true><<<dim3(INNER/64, NN/128, NE), 256, 0, stream>>>(
      tokb, perm, w1t, be1, cnt, poff, h1);
  gemm_swiglu_kernel<INNER, false><<<dim3(INNER/64, NN/128, NE), 256, 0, stream>>>(
      h1, nullptr, w2t, be2, cnt, poff, h2b);
  gemm_out_kernel<<<dim3(DIM/128, NN/128, NE), 256, 0, stream>>>(
      h2b, w3t, be3, cnt, poff, perm, pw, y);

  hipMemsetAsync(pooled, 0, (size_t)NB*DIM*4, stream);
  pooled_kernel<<<NB*8, 384, 0, stream>>>(x, sres, y, pooled);
  gate_kernel<<<NB, 128, 0, stream>>>(pooled, sw1, sb1, sw2, sb2, gate);
  final_kernel<<<(NN*DIM/4)/256, 256, 0, stream>>>(res, y, gate, out);
}

// Round 2
// 671.452 us; speedup vs baseline: 1.0372x; 1.0372x over previous
//
#include <hip/hip_runtime.h>
#include <stdint.h>

#define DIM 384
#define INNER 1536
#define H2X 3072
#define NE 5
#define NB 4
#define NT 1024
#define NN (NB*NT)
#define KSZ 31
#define SQZ 48
#define NASSIGN (NN*2)

typedef float floatx4 __attribute__((ext_vector_type(4)));
typedef __bf16 bf16x8 __attribute__((ext_vector_type(8)));

__device__ __forceinline__ unsigned short f2bs(float f){
  union { float f; uint32_t u; } v; v.f = f;
  uint32_t r = (v.u + 0x7fffu + ((v.u >> 16) & 1u)) >> 16;
  return (unsigned short)r;
}
__device__ __forceinline__ float bs2f(unsigned short s){
  union { uint32_t u; float f; } v; v.u = ((uint32_t)s) << 16; return v.f;
}
__device__ __forceinline__ float fsigmoid(float x){ return 1.f/(1.f+__expf(-x)); }

// async global->LDS, 16B per lane; LDS dest = wave-uniform base + lane*16
__device__ __forceinline__ void gload16(const unsigned short* g, unsigned short* l){
  __builtin_amdgcn_global_load_lds(
    reinterpret_cast<const __attribute__((address_space(1))) unsigned int*>(
        reinterpret_cast<uintptr_t>(g)),
    reinterpret_cast<__attribute__((address_space(3))) unsigned int*>(
        (unsigned int)reinterpret_cast<uintptr_t>(l)),
    16, 0, 0);
}

// ---------------- transpose + cast f32 [z][R][C] -> bf16 [z][C][R] ----------------
// block handles 64 rows x 32 cols; threads (32,8)
__global__ __launch_bounds__(256) void transpose_cast_kernel(const float* __restrict__ in,
    unsigned short* __restrict__ out, int R, int C){
  __shared__ float tile[32][65];   // [c][r]
  int z = blockIdx.z;
  in  += (size_t)z * R * C;
  out += (size_t)z * R * C;
  int c0 = blockIdx.x*32, r0 = blockIdx.y*64;
  int tx = threadIdx.x, ty = threadIdx.y;
  #pragma unroll
  for (int i=0;i<8;i++){
    int r = ty + i*8;
    tile[tx][r] = in[(size_t)(r0+r)*C + c0 + tx];
  }
  __syncthreads();
  #pragma unroll
  for (int i=0;i<4;i++){
    int c = ty + i*8;
    uint32_t lo = f2bs(tile[c][2*tx]);
    uint32_t hi = f2bs(tile[c][2*tx+1]);
    *(uint32_t*)&out[(size_t)(c0+c)*R + r0 + 2*tx] = lo | (hi<<16);
  }
}

// ---------------- LayerNorm: res -> x ----------------
__global__ __launch_bounds__(128) void ln_kernel(const float* __restrict__ res,
    const float* __restrict__ g, const float* __restrict__ b, float* __restrict__ x){
  int row = blockIdx.x; int tid = threadIdx.x;
  const float* r = res + (size_t)row*DIM;
  float v0=r[tid], v1=r[tid+128], v2=r[tid+256];
  float s = v0+v1+v2;
  #pragma unroll
  for(int o=32;o;o>>=1) s += __shfl_down(s,o);
  __shared__ float sb[2];
  int lane = tid&63, w = tid>>6;
  if(lane==0) sb[w]=s;
  __syncthreads();
  float mean = (sb[0]+sb[1]) * (1.f/DIM);
  __syncthreads();
  float d0=v0-mean,d1=v1-mean,d2=v2-mean;
  float q = d0*d0+d1*d1+d2*d2;
  #pragma unroll
  for(int o=32;o;o>>=1) q += __shfl_down(q,o);
  if(lane==0) sb[w]=q;
  __syncthreads();
  float rstd = rsqrtf((sb[0]+sb[1])*(1.f/DIM) + 1e-5f);
  float* xo = x + (size_t)row*DIM;
  xo[tid]     = d0*rstd*g[tid]     + b[tid];
  xo[tid+128] = d1*rstd*g[tid+128] + b[tid+128];
  xo[tid+256] = d2*rstd*g[tid+256] + b[tid+256];
}

// ---------------- depthwise conv over time: x -> h (f32), tok_bf16, y=h ----------------
#define CTT 8
__global__ __launch_bounds__(384) void conv_kernel(const float* __restrict__ x,
    const float* __restrict__ cw, const float* __restrict__ cb,
    float* __restrict__ h, unsigned short* __restrict__ tokb, float* __restrict__ y){
  __shared__ float tile[(CTT+30)*DIM];
  int b = blockIdx.y, t0 = blockIdx.x*CTT;
  int tid = threadIdx.x;
  for (int r=0;r<CTT+30;r++){
    int gt = t0 - 15 + r;
    float v = (gt>=0 && gt<NT) ? x[((size_t)b*NT+gt)*DIM + tid] : 0.f;
    tile[r*DIM+tid] = v;
  }
  __syncthreads();
  float w[KSZ];
  #pragma unroll
  for(int k=0;k<KSZ;k++) w[k] = cw[tid*KSZ+k];
  float bias = cb[tid];
  for(int t=0;t<CTT;t++){
    float acc = bias;
    #pragma unroll
    for(int k=0;k<KSZ;k++) acc += tile[(t+k)*DIM+tid]*w[k];
    size_t o = ((size_t)b*NT + t0 + t)*DIM + tid;
    h[o]=acc; y[o]=acc; tokb[o]=f2bs(acc);
  }
}

// ---------------- router GEMM1: g1 = silu(tok @ rw1 + rb1), bf16 out ----------------
__global__ __launch_bounds__(256) void router_g1_kernel(const unsigned short* __restrict__ tokb,
    const unsigned short* __restrict__ rw1t, const float* __restrict__ rb1,
    unsigned short* __restrict__ g1){
  __shared__ alignas(16) unsigned short sA[128*32];
  __shared__ alignas(16) unsigned short sB[128*32];
  int tid = threadIdx.x;
  int n0 = blockIdx.x*128, m0 = blockIdx.y*128;
  int lane = tid&63, wid = tid>>6, wm = wid&1, wn = wid>>1;
  int l15 = lane&15, quad = lane>>4;
  floatx4 acc[4][4];
  #pragma unroll
  for(int i=0;i<4;i++)
    #pragma unroll
    for(int j=0;j<4;j++) acc[i][j]=(floatx4){0.f,0.f,0.f,0.f};
  int rA = tid>>2, c8 = tid&3;
  const unsigned short* a0p = tokb + (size_t)(m0+rA)*DIM;
  const unsigned short* a1p = tokb + (size_t)(m0+64+rA)*DIM;
  const unsigned short* b0p = rw1t + (size_t)(n0+rA)*DIM;
  const unsigned short* b1p = rw1t + (size_t)(n0+64+rA)*DIM;
  for(int kt=0; kt<DIM; kt+=32){
    __syncthreads();
    gload16(a0p + kt + c8*8, &sA[wid*512]);
    gload16(a1p + kt + c8*8, &sA[2048 + wid*512]);
    gload16(b0p + kt + c8*8, &sB[wid*512]);
    gload16(b1p + kt + c8*8, &sB[2048 + wid*512]);
    __syncthreads();
    bf16x8 af[4], bfr[4];
    #pragma unroll
    for(int mi=0;mi<4;mi++) af[mi] = *(const bf16x8*)&sA[(wm*64+mi*16+l15)*32 + quad*8];
    #pragma unroll
    for(int ni=0;ni<4;ni++) bfr[ni] = *(const bf16x8*)&sB[(wn*64+ni*16+l15)*32 + quad*8];
    #pragma unroll
    for(int mi=0;mi<4;mi++)
      #pragma unroll
      for(int ni=0;ni<4;ni++)
        acc[mi][ni] = __builtin_amdgcn_mfma_f32_16x16x32_bf16(af[mi], bfr[ni], acc[mi][ni],0,0,0);
  }
  #pragma unroll
  for(int ni=0;ni<4;ni++){
    int col = n0 + wn*64 + ni*16 + l15;
    float bias = rb1[col];
    #pragma unroll
    for(int mi=0;mi<4;mi++){
      int rowb = m0 + wm*64 + mi*16 + quad*4;
      #pragma unroll
      for(int r=0;r<4;r++){
        float v = acc[mi][ni][r] + bias;
        g1[(size_t)(rowb+r)*DIM + col] = f2bs(v*fsigmoid(v));
      }
    }
  }
}

// ---------------- router2: scores, top2, softmax, counts ----------------
__global__ __launch_bounds__(256) void router2_kernel(const unsigned short* __restrict__ g1,
    const float* __restrict__ rw2, const float* __restrict__ rb2,
    int* __restrict__ ridx, float* __restrict__ rwt, int* __restrict__ cnt){
  int wid = threadIdx.x>>6, lane = threadIdx.x&63;
  int n = blockIdx.x*4 + wid;
  float s[NE]={0.f,0.f,0.f,0.f,0.f};
  #pragma unroll
  for(int i=0;i<6;i++){
    int d = lane + i*64;
    float gv = bs2f(g1[(size_t)n*DIM+d]);
    #pragma unroll
    for(int e=0;e<NE;e++) s[e] += gv * rw2[d*NE+e];
  }
  #pragma unroll
  for(int e=0;e<NE;e++)
    #pragma unroll
    for(int o=32;o;o>>=1) s[e] += __shfl_down(s[e],o);
  if(lane==0){
    float r[NE];
    #pragma unroll
    for(int e=0;e<NE;e++) r[e]=s[e]+rb2[e];
    int e0=0;
    for(int e=1;e<NE;e++) if(r[e]>r[e0]) e0=e;
    int e1=-1;
    for(int e=0;e<NE;e++){ if(e==e0) continue; if(e1<0||r[e]>r[e1]) e1=e; }
    float w0 = 1.f/(1.f+__expf(r[e1]-r[e0]));
    ridx[2*n]=e0; ridx[2*n+1]=e1;
    rwt[2*n]=w0; rwt[2*n+1]=1.f-w0;
    atomicAdd(&cnt[e0],1); atomicAdd(&cnt[e1],1);
  }
}

__global__ void prefix_kernel(const int* __restrict__ cnt, int* __restrict__ poff, int* __restrict__ cursor){
  if(threadIdx.x==0 && blockIdx.x==0){
    int run=0;
    for(int e=0;e<NE;e++){ poff[e]=run; cursor[e]=run; run+=cnt[e]; }
  }
}

__global__ __launch_bounds__(256) void fill_kernel(const int* __restrict__ ridx,
    const float* __restrict__ rwt, int* __restrict__ cursor,
    int* __restrict__ perm, float* __restrict__ pw){
  int i = blockIdx.x*256 + threadIdx.x;
  int e = ridx[i];
  int pos = atomicAdd(&cursor[e],1);
  perm[pos] = i>>1;
  pw[pos] = rwt[i];
}

// ---------------- expert GEMM with fused SwiGLU ----------------
template<int KDIM, bool GATHER>
__global__ __launch_bounds__(256) void gemm_swiglu_kernel(
    const unsigned short* __restrict__ A, const int* __restrict__ perm,
    const unsigned short* __restrict__ wt, const float* __restrict__ bias,
    const int* __restrict__ cnt, const int* __restrict__ poff,
    unsigned short* __restrict__ out){
  int e = blockIdx.z;
  int cn = cnt[e];
  int mtile = blockIdx.y;
  if (mtile*128 >= cn) return;
  int base = poff[e];
  int j0 = blockIdx.x*64;
  int tid=threadIdx.x, lane=tid&63, wid=tid>>6, wm=wid&1, wn=wid>>1;
  int l15=lane&15, quad=lane>>4;
  __shared__ alignas(16) unsigned short sA[128*32];
  __shared__ alignas(16) unsigned short sBa[64*32];
  __shared__ alignas(16) unsigned short sBg[64*32];
  int rA = tid>>2, c8 = tid&3;
  int lr0 = mtile*128 + rA, lr1 = lr0+64;
  int p0 = base + min(lr0, cn-1);
  int p1 = base + min(lr1, cn-1);
  const unsigned short *a0p, *a1p;
  if constexpr (GATHER){
    a0p = A + (size_t)perm[p0]*KDIM;
    a1p = A + (size_t)perm[p1]*KDIM;
  } else {
    a0p = A + (size_t)p0*KDIM;
    a1p = A + (size_t)p1*KDIM;
  }
  const unsigned short* bap = wt + ((size_t)e*H2X + j0 + rA)*KDIM;
  const unsigned short* bgp = wt + ((size_t)e*H2X + INNER + j0 + rA)*KDIM;
  floatx4 aca[4][2], acg[4][2];
  #pragma unroll
  for(int i=0;i<4;i++)
    #pragma unroll
    for(int j=0;j<2;j++){ aca[i][j]=(floatx4){0.f,0.f,0.f,0.f}; acg[i][j]=(floatx4){0.f,0.f,0.f,0.f}; }
  for(int kt=0; kt<KDIM; kt+=32){
    __syncthreads();
    gload16(a0p + kt + c8*8, &sA[wid*512]);
    gload16(a1p + kt + c8*8, &sA[2048 + wid*512]);
    gload16(bap + kt + c8*8, &sBa[wid*512]);
    gload16(bgp + kt + c8*8, &sBg[wid*512]);
    __syncthreads();
    bf16x8 af[4], ba[2], bg[2];
    #pragma unroll
    for(int mi=0;mi<4;mi++) af[mi] = *(const bf16x8*)&sA[(wm*64+mi*16+l15)*32 + quad*8];
    #pragma unroll
    for(int ni=0;ni<2;ni++){
      ba[ni] = *(const bf16x8*)&sBa[(wn*32+ni*16+l15)*32 + quad*8];
      bg[ni] = *(const bf16x8*)&sBg[(wn*32+ni*16+l15)*32 + quad*8];
    }
    #pragma unroll
    for(int mi=0;mi<4;mi++)
      #pragma unroll
      for(int ni=0;ni<2;ni++){
        aca[mi][ni] = __builtin_amdgcn_mfma_f32_16x16x32_bf16(af[mi], ba[ni], aca[mi][ni],0,0,0);
        acg[mi][ni] = __builtin_amdgcn_mfma_f32_16x16x32_bf16(af[mi], bg[ni], acg[mi][ni],0,0,0);
      }
  }
  #pragma unroll
  for(int ni=0;ni<2;ni++){
    int j = j0 + wn*32 + ni*16 + l15;
    float ba_ = bias[e*H2X + j];
    float bg_ = bias[e*H2X + INNER + j];
    #pragma unroll
    for(int mi=0;mi<4;mi++){
      int rl = wm*64 + mi*16 + quad*4;
      #pragma unroll
      for(int r=0;r<4;r++){
        int row = mtile*128 + rl + r;
        if(row < cn){
          float a = aca[mi][ni][r] + ba_;
          float g = acg[mi][ni][r] + bg_;
          out[(size_t)(base+row)*INNER + j] = f2bs(a * g * fsigmoid(g));
        }
      }
    }
  }
}

// ---------------- expert output GEMM + weighted scatter into y ----------------
__global__ __launch_bounds__(256) void gemm_out_kernel(
    const unsigned short* __restrict__ h2, const unsigned short* __restrict__ w3t,
    const float* __restrict__ be3, const int* __restrict__ cnt, const int* __restrict__ poff,
    const int* __restrict__ perm, const float* __restrict__ pw, float* __restrict__ y){
  int e = blockIdx.z;
  int cn = cnt[e];
  int mtile = blockIdx.y;
  if (mtile*128 >= cn) return;
  int base = poff[e];
  int n0 = blockIdx.x*128;
  int tid=threadIdx.x, lane=tid&63, wid=tid>>6, wm=wid&1, wn=wid>>1;
  int l15=lane&15, quad=lane>>4;
  __shared__ alignas(16) unsigned short sA[128*32];
  __shared__ alignas(16) unsigned short sB[128*32];
  int rA = tid>>2, c8 = tid&3;
  int lr0 = mtile*128 + rA, lr1 = lr0+64;
  const unsigned short* a0p = h2 + (size_t)(base + min(lr0, cn-1))*INNER;
  const unsigned short* a1p = h2 + (size_t)(base + min(lr1, cn-1))*INNER;
  const unsigned short* b0p = w3t + ((size_t)e*DIM + n0 + rA)*INNER;
  const unsigned short* b1p = w3t + ((size_t)e*DIM + n0 + 64 + rA)*INNER;
  floatx4 acc[4][4];
  #pragma unroll
  for(int i=0;i<4;i++)
    #pragma unroll
    for(int j=0;j<4;j++) acc[i][j]=(floatx4){0.f,0.f,0.f,0.f};
  for(int kt=0; kt<INNER; kt+=32){
    __syncthreads();
    gload16(a0p + kt + c8*8, &sA[wid*512]);
    gload16(a1p + kt + c8*8, &sA[2048 + wid*512]);
    gload16(b0p + kt + c8*8, &sB[wid*512]);
    gload16(b1p + kt + c8*8, &sB[2048 + wid*512]);
    __syncthreads();
    bf16x8 af[4], bfr[4];
    #pragma unroll
    for(int mi=0;mi<4;mi++) af[mi] = *(const bf16x8*)&sA[(wm*64+mi*16+l15)*32 + quad*8];
    #pragma unroll
    for(int ni=0;ni<4;ni++) bfr[ni] = *(const bf16x8*)&sB[(wn*64+ni*16+l15)*32 + quad*8];
    #pragma unroll
    for(int mi=0;mi<4;mi++)
      #pragma unroll
      for(int ni=0;ni<4;ni++)
        acc[mi][ni] = __builtin_amdgcn_mfma_f32_16x16x32_bf16(af[mi], bfr[ni], acc[mi][ni],0,0,0);
  }
  #pragma unroll
  for(int ni=0;ni<4;ni++){
    int col = n0 + wn*64 + ni*16 + l15;
    float b3 = be3[e*DIM + col];
    #pragma unroll
    for(int mi=0;mi<4;mi++){
      int rl = wm*64 + mi*16 + quad*4;
      #pragma unroll
      for(int r=0;r<4;r++){
        int row = mtile*128 + rl + r;
        if(row < cn){
          int pos = base + row;
          float wv = pw[pos];
          int tokn = perm[pos];
          atomicAdd(&y[(size_t)tokn*DIM + col], wv*(acc[mi][ni][r] + b3));
        }
      }
    }
  }
}

// ---------------- senet pooled / gate / final ----------------
__global__ __launch_bounds__(384) void pooled_kernel(const float* __restrict__ x,
    const float* __restrict__ sres, const float* __restrict__ y, float* __restrict__ pooled){
  int b = blockIdx.x>>3, c = blockIdx.x&7;
  int d = threadIdx.x;
  float sr = sres[d];
  float s=0.f;
  for(int t=c*128;t<c*128+128;t++){
    size_t o=((size_t)b*NT+t)*DIM+d;
    s += x[o]*sr + y[o];
  }
  atomicAdd(&pooled[b*DIM+d], s*(1.f/NT));
}

__global__ __launch_bounds__(128) void gate_kernel(const float* __restrict__ pooled,
    const float* __restrict__ sw1, const float* __restrict__ sb1,
    const float* __restrict__ sw2, const float* __restrict__ sb2, float* __restrict__ gate){
  int b=blockIdx.x; int tid=threadIdx.x;
  __shared__ float sp[DIM];
  __shared__ float sh[SQZ];
  for(int i=tid;i<DIM;i+=128) sp[i]=pooled[b*DIM+i];
  __syncthreads();
  if(tid<SQZ){
    float a=sb1[tid];
    for(int d=0;d<DIM;d++) a += sp[d]*sw1[d*SQZ+tid];
    sh[tid]= a*fsigmoid(a);
  }
  __syncthreads();
  for(int i=tid;i<DIM;i+=128){
    float a=sb2[i];
    #pragma unroll
    for(int j=0;j<SQZ;j++) a += sh[j]*sw2[j*DIM+i];
    gate[b*DIM+i]=fsigmoid(a);
  }
}

__global__ __launch_bounds__(256) void final_kernel(const float* __restrict__ res,
    const float* __restrict__ y, const float* __restrict__ gate, float* __restrict__ out){
  int i4 = blockIdx.x*256+threadIdx.x;
  int d4 = i4 % 96; int row = i4 / 96; int b = row>>10;
  float4 r = *(const float4*)&res[(size_t)i4*4];
  float4 yv = *(const float4*)&y[(size_t)i4*4];
  float4 gv = *(const float4*)&gate[b*DIM + d4*4];
  float4 o;
  o.x=r.x+yv.x*gv.x; o.y=r.y+yv.y*gv.y; o.z=r.z+yv.z*gv.z; o.w=r.w+yv.w*gv.w;
  *(float4*)&out[(size_t)i4*4]=o;
}

extern "C" void kernel_launch(void* const* d_in, const int* in_sizes, int n_in,
                              void* d_out, int out_size, void* d_ws, size_t ws_size,
                              hipStream_t stream) {
  (void)in_sizes; (void)n_in; (void)out_size; (void)ws_size;
  const float* res   = (const float*)d_in[0];
  const float* ln_g  = (const float*)d_in[1];
  const float* ln_b  = (const float*)d_in[2];
  const float* conv_w= (const float*)d_in[3];
  const float* conv_b= (const float*)d_in[4];
  const float* rw1   = (const float*)d_in[5];
  const float* rb1   = (const float*)d_in[6];
  const float* rw2   = (const float*)d_in[7];
  const float* rb2   = (const float*)d_in[8];
  const float* we1   = (const float*)d_in[9];
  const float* be1   = (const float*)d_in[10];
  const float* we2   = (const float*)d_in[11];
  const float* be2   = (const float*)d_in[12];
  const float* we3   = (const float*)d_in[13];
  const float* be3   = (const float*)d_in[14];
  const float* sw1   = (const float*)d_in[15];
  const float* sb1   = (const float*)d_in[16];
  const float* sw2   = (const float*)d_in[17];
  const float* sb2   = (const float*)d_in[18];
  const float* sres  = (const float*)d_in[19];
  float* out = (float*)d_out;

  char* ws = (char*)d_ws;
  size_t off = 0;
  auto alloc = [&](size_t bytes)->void*{ void* p = ws + off; off = (off + bytes + 255) & ~(size_t)255; return p; };
  float*          x     = (float*)alloc((size_t)NN*DIM*4);
  float*          h     = (float*)alloc((size_t)NN*DIM*4);
  float*          y     = (float*)alloc((size_t)NN*DIM*4);
  unsigned short* tokb  = (unsigned short*)alloc((size_t)NN*DIM*2);
  unsigned short* g1    = (unsigned short*)alloc((size_t)NN*DIM*2);
  unsigned short* w1t   = (unsigned short*)alloc((size_t)NE*H2X*DIM*2);
  unsigned short* w2t   = (unsigned short*)alloc((size_t)NE*H2X*INNER*2);
  unsigned short* w3t   = (unsigned short*)alloc((size_t)NE*DIM*INNER*2);
  unsigned short* rw1t  = (unsigned short*)alloc((size_t)DIM*DIM*2);
  unsigned short* h1    = (unsigned short*)alloc((size_t)NASSIGN*INNER*2);
  unsigned short* h2b   = (unsigned short*)alloc((size_t)NASSIGN*INNER*2);
  int*            ridx  = (int*)alloc((size_t)NASSIGN*4);
  float*          rwt   = (float*)alloc((size_t)NASSIGN*4);
  int*            perm  = (int*)alloc((size_t)NASSIGN*4);
  float*          pw    = (float*)alloc((size_t)NASSIGN*4);
  int*            cnt   = (int*)alloc(64);
  int*            poff  = (int*)alloc(64);
  int*            cursor= (int*)alloc(64);
  float*          pooled= (float*)alloc((size_t)NB*DIM*4);
  float*          gate  = (float*)alloc((size_t)NB*DIM*4);

  dim3 tb(32,8);
  transpose_cast_kernel<<<dim3(H2X/32, DIM/64, NE), tb, 0, stream>>>(we1, w1t, DIM, H2X);
  transpose_cast_kernel<<<dim3(H2X/32, INNER/64, NE), tb, 0, stream>>>(we2, w2t, INNER, H2X);
  transpose_cast_kernel<<<dim3(DIM/32, INNER/64, NE), tb, 0, stream>>>(we3, w3t, INNER, DIM);
  transpose_cast_kernel<<<dim3(DIM/32, DIM/64, 1), tb, 0, stream>>>(rw1, rw1t, DIM, DIM);

  ln_kernel<<<NN, 128, 0, stream>>>(res, ln_g, ln_b, x);
  conv_kernel<<<dim3(NT/CTT, NB), 384, 0, stream>>>(x, conv_w, conv_b, h, tokb, y);

  hipMemsetAsync(cnt, 0, 64, stream);
  router_g1_kernel<<<dim3(DIM/128, NN/128), 256, 0, stream>>>(tokb, rw1t, rb1, g1);
  router2_kernel<<<NN/4, 256, 0, stream>>>(g1, rw2, rb2, ridx, rwt, cnt);
  prefix_kernel<<<1, 64, 0, stream>>>(cnt, poff, cursor);
  fill_kernel<<<NASSIGN/256, 256, 0, stream>>>(ridx, rwt, cursor, perm, pw);

  gemm_swiglu_kernel<DIM, true><<<dim3(INNER/64, NN/128, NE), 256, 0, stream>>>(
      tokb, perm, w1t, be1, cnt, poff, h1);
  gemm_swiglu_kernel<INNER, false><<<dim3(INNER/64, NN/128, NE), 256, 0, stream>>>(
      h1, nullptr, w2t, be2, cnt, poff, h2b);
  gemm_out_kernel<<<dim3(DIM/128, NN/128, NE), 256, 0, stream>>>(
      h2b, w3t, be3, cnt, poff, perm, pw, y);

  hipMemsetAsync(pooled, 0, (size_t)NB*DIM*4, stream);
  pooled_kernel<<<NB*8, 384, 0, stream>>>(x, sres, y, pooled);
  gate_kernel<<<NB, 128, 0, stream>>>(pooled, sw1, sb1, sw2, sb2, gate);
  final_kernel<<<(NN*DIM/4)/256, 256, 0, stream>>>(res, y, gate, out);
}

// Round 3
// 642.340 us; speedup vs baseline: 1.0842x; 1.0453x over previous
//
#include <hip/hip_runtime.h>
#include <stdint.h>

#define DIM 384
#define INNER 1536
#define H2X 3072
#define NE 5
#define NB 4
#define NT 1024
#define NN (NB*NT)
#define KSZ 31
#define SQZ 48
#define NASSIGN (NN*2)

typedef float floatx4 __attribute__((ext_vector_type(4)));
typedef __bf16 bf16x8 __attribute__((ext_vector_type(8)));

__device__ __forceinline__ unsigned short f2bs(float f){
  union { float f; uint32_t u; } v; v.f = f;
  uint32_t r = (v.u + 0x7fffu + ((v.u >> 16) & 1u)) >> 16;
  return (unsigned short)r;
}
__device__ __forceinline__ float bs2f(unsigned short s){
  union { uint32_t u; float f; } v; v.u = ((uint32_t)s) << 16; return v.f;
}
__device__ __forceinline__ float fsigmoid(float x){ return 1.f/(1.f+__expf(-x)); }

__device__ __forceinline__ void gload16(const unsigned short* g, unsigned short* l){
  __builtin_amdgcn_global_load_lds(
    reinterpret_cast<const __attribute__((address_space(1))) unsigned int*>(
        reinterpret_cast<uintptr_t>(g)),
    reinterpret_cast<__attribute__((address_space(3))) unsigned int*>(
        (unsigned int)reinterpret_cast<uintptr_t>(l)),
    16, 0, 0);
}

__device__ __forceinline__ int prefix_cnt(const int* __restrict__ cnt, int e){
  int base = 0;
  #pragma unroll
  for(int k=0;k<NE;k++) base += (k<e) ? cnt[k] : 0;
  return base;
}

// ---------------- transpose + cast f32 [z][R][C] -> bf16 [z][C][R] ----------------
__global__ __launch_bounds__(256) void transpose_cast_kernel(const float* __restrict__ in,
    unsigned short* __restrict__ out, int R, int C){
  __shared__ float tile[32][65];
  int z = blockIdx.z;
  in  += (size_t)z * R * C;
  out += (size_t)z * R * C;
  int c0 = blockIdx.x*32, r0 = blockIdx.y*64;
  int tx = threadIdx.x, ty = threadIdx.y;
  #pragma unroll
  for (int i=0;i<8;i++){
    int r = ty + i*8;
    tile[tx][r] = in[(size_t)(r0+r)*C + c0 + tx];
  }
  __syncthreads();
  #pragma unroll
  for (int i=0;i<4;i++){
    int c = ty + i*8;
    uint32_t lo = f2bs(tile[c][2*tx]);
    uint32_t hi = f2bs(tile[c][2*tx+1]);
    *(uint32_t*)&out[(size_t)(c0+c)*R + r0 + 2*tx] = lo | (hi<<16);
  }
}

// ---------------- LayerNorm: res -> x ----------------
__global__ __launch_bounds__(128) void ln_kernel(const float* __restrict__ res,
    const float* __restrict__ g, const float* __restrict__ b, float* __restrict__ x){
  int row = blockIdx.x; int tid = threadIdx.x;
  const float* r = res + (size_t)row*DIM;
  float v0=r[tid], v1=r[tid+128], v2=r[tid+256];
  float s = v0+v1+v2;
  #pragma unroll
  for(int o=32;o;o>>=1) s += __shfl_down(s,o);
  __shared__ float sb[2];
  int lane = tid&63, w = tid>>6;
  if(lane==0) sb[w]=s;
  __syncthreads();
  float mean = (sb[0]+sb[1]) * (1.f/DIM);
  __syncthreads();
  float d0=v0-mean,d1=v1-mean,d2=v2-mean;
  float q = d0*d0+d1*d1+d2*d2;
  #pragma unroll
  for(int o=32;o;o>>=1) q += __shfl_down(q,o);
  if(lane==0) sb[w]=q;
  __syncthreads();
  float rstd = rsqrtf((sb[0]+sb[1])*(1.f/DIM) + 1e-5f);
  float* xo = x + (size_t)row*DIM;
  xo[tid]     = d0*rstd*g[tid]     + b[tid];
  xo[tid+128] = d1*rstd*g[tid+128] + b[tid+128];
  xo[tid+256] = d2*rstd*g[tid+256] + b[tid+256];
}

// ---------------- depthwise conv: x -> tok_bf16, y ----------------
#define CTT 8
__global__ __launch_bounds__(384) void conv_kernel(const float* __restrict__ x,
    const float* __restrict__ cw, const float* __restrict__ cb,
    unsigned short* __restrict__ tokb, float* __restrict__ y){
  __shared__ float tile[(CTT+30)*DIM];
  int b = blockIdx.y, t0 = blockIdx.x*CTT;
  int tid = threadIdx.x;
  for (int r=0;r<CTT+30;r++){
    int gt = t0 - 15 + r;
    float v = (gt>=0 && gt<NT) ? x[((size_t)b*NT+gt)*DIM + tid] : 0.f;
    tile[r*DIM+tid] = v;
  }
  __syncthreads();
  float w[KSZ];
  #pragma unroll
  for(int k=0;k<KSZ;k++) w[k] = cw[tid*KSZ+k];
  float bias = cb[tid];
  for(int t=0;t<CTT;t++){
    float acc = bias;
    #pragma unroll
    for(int k=0;k<KSZ;k++) acc += tile[(t+k)*DIM+tid]*w[k];
    size_t o = ((size_t)b*NT + t0 + t)*DIM + tid;
    y[o]=acc; tokb[o]=f2bs(acc);
  }
}

// ---------------- router GEMM1 ----------------
__global__ __launch_bounds__(256) void router_g1_kernel(const unsigned short* __restrict__ tokb,
    const unsigned short* __restrict__ rw1t, const float* __restrict__ rb1,
    unsigned short* __restrict__ g1){
  __shared__ alignas(16) unsigned short sA[128*32];
  __shared__ alignas(16) unsigned short sB[128*32];
  int tid = threadIdx.x;
  int n0 = blockIdx.x*128, m0 = blockIdx.y*128;
  int lane = tid&63, wid = tid>>6, wm = wid&1, wn = wid>>1;
  int l15 = lane&15, quad = lane>>4;
  floatx4 acc[4][4];
  #pragma unroll
  for(int i=0;i<4;i++)
    #pragma unroll
    for(int j=0;j<4;j++) acc[i][j]=(floatx4){0.f,0.f,0.f,0.f};
  int rA = tid>>2, c8 = tid&3;
  const unsigned short* a0p = tokb + (size_t)(m0+rA)*DIM;
  const unsigned short* a1p = tokb + (size_t)(m0+64+rA)*DIM;
  const unsigned short* b0p = rw1t + (size_t)(n0+rA)*DIM;
  const unsigned short* b1p = rw1t + (size_t)(n0+64+rA)*DIM;
  for(int kt=0; kt<DIM; kt+=32){
    __syncthreads();
    gload16(a0p + kt + c8*8, &sA[wid*512]);
    gload16(a1p + kt + c8*8, &sA[2048 + wid*512]);
    gload16(b0p + kt + c8*8, &sB[wid*512]);
    gload16(b1p + kt + c8*8, &sB[2048 + wid*512]);
    __syncthreads();
    bf16x8 af[4], bfr[4];
    #pragma unroll
    for(int mi=0;mi<4;mi++) af[mi] = *(const bf16x8*)&sA[(wm*64+mi*16+l15)*32 + quad*8];
    #pragma unroll
    for(int ni=0;ni<4;ni++) bfr[ni] = *(const bf16x8*)&sB[(wn*64+ni*16+l15)*32 + quad*8];
    #pragma unroll
    for(int mi=0;mi<4;mi++)
      #pragma unroll
      for(int ni=0;ni<4;ni++)
        acc[mi][ni] = __builtin_amdgcn_mfma_f32_16x16x32_bf16(af[mi], bfr[ni], acc[mi][ni],0,0,0);
  }
  #pragma unroll
  for(int ni=0;ni<4;ni++){
    int col = n0 + wn*64 + ni*16 + l15;
    float bias = rb1[col];
    #pragma unroll
    for(int mi=0;mi<4;mi++){
      int rowb = m0 + wm*64 + mi*16 + quad*4;
      #pragma unroll
      for(int r=0;r<4;r++){
        float v = acc[mi][ni][r] + bias;
        g1[(size_t)(rowb+r)*DIM + col] = f2bs(v*fsigmoid(v));
      }
    }
  }
}

// ---------------- router2 ----------------
__global__ __launch_bounds__(256) void router2_kernel(const unsigned short* __restrict__ g1,
    const float* __restrict__ rw2, const float* __restrict__ rb2,
    int* __restrict__ ridx, float* __restrict__ rwt, int* __restrict__ cnt){
  int wid = threadIdx.x>>6, lane = threadIdx.x&63;
  int n = blockIdx.x*4 + wid;
  float s[NE]={0.f,0.f,0.f,0.f,0.f};
  #pragma unroll
  for(int i=0;i<6;i++){
    int d = lane + i*64;
    float gv = bs2f(g1[(size_t)n*DIM+d]);
    #pragma unroll
    for(int e=0;e<NE;e++) s[e] += gv * rw2[d*NE+e];
  }
  #pragma unroll
  for(int e=0;e<NE;e++)
    #pragma unroll
    for(int o=32;o;o>>=1) s[e] += __shfl_down(s[e],o);
  if(lane==0){
    float r[NE];
    #pragma unroll
    for(int e=0;e<NE;e++) r[e]=s[e]+rb2[e];
    int e0=0;
    for(int e=1;e<NE;e++) if(r[e]>r[e0]) e0=e;
    int e1=-1;
    for(int e=0;e<NE;e++){ if(e==e0) continue; if(e1<0||r[e]>r[e1]) e1=e; }
    float w0 = 1.f/(1.f+__expf(r[e1]-r[e0]));
    ridx[2*n]=e0; ridx[2*n+1]=e1;
    rwt[2*n]=w0; rwt[2*n+1]=1.f-w0;
    atomicAdd(&cnt[e0],1); atomicAdd(&cnt[e1],1);
  }
}

// fill: computes prefix locally from cnt, uses cnt2 as cursor, writes inverse map
__global__ __launch_bounds__(256) void fill_kernel(const int* __restrict__ ridx,
    const float* __restrict__ rwt, const int* __restrict__ cnt, int* __restrict__ cnt2,
    int* __restrict__ perm, float* __restrict__ pw, int* __restrict__ inv){
  int i = blockIdx.x*256 + threadIdx.x;
  int e = ridx[i];
  int base = prefix_cnt(cnt, e);
  int pos = base + atomicAdd(&cnt2[e],1);
  perm[pos] = i>>1;
  pw[pos] = rwt[i];
  inv[i] = pos;
}

// compact gathered token rows: tokc[pos] = tokb[perm[pos]]
__global__ __launch_bounds__(768) void compact_kernel(const unsigned short* __restrict__ tokb,
    const int* __restrict__ perm, unsigned short* __restrict__ tokc){
  int tid = threadIdx.x;
  int row = blockIdx.x*8 + tid/96;
  int c = tid%96;
  int src = perm[row];
  ((uint64_t*)&tokc[(size_t)row*DIM])[c] = ((const uint64_t*)&tokb[(size_t)src*DIM])[c];
}

// ---------------- expert GEMM with fused SwiGLU (contiguous A) ----------------
template<int KDIM>
__global__ __launch_bounds__(256) void gemm_swiglu_kernel(
    const unsigned short* __restrict__ A,
    const unsigned short* __restrict__ wt, const float* __restrict__ bias,
    const int* __restrict__ cnt, unsigned short* __restrict__ out){
  int e = blockIdx.z;
  int cn = cnt[e];
  int mtile = blockIdx.y;
  if (mtile*128 >= cn) return;
  int base = prefix_cnt(cnt, e);
  int j0 = blockIdx.x*64;
  int tid=threadIdx.x, lane=tid&63, wid=tid>>6, wm=wid&1, wn=wid>>1;
  int l15=lane&15, quad=lane>>4;
  __shared__ alignas(16) unsigned short sA[128*32];
  __shared__ alignas(16) unsigned short sBa[64*32];
  __shared__ alignas(16) unsigned short sBg[64*32];
  int rA = tid>>2, c8 = tid&3;
  int lr0 = mtile*128 + rA, lr1 = lr0+64;
  const unsigned short* a0p = A + (size_t)(base + min(lr0, cn-1))*KDIM;
  const unsigned short* a1p = A + (size_t)(base + min(lr1, cn-1))*KDIM;
  const unsigned short* bap = wt + ((size_t)e*H2X + j0 + rA)*KDIM;
  const unsigned short* bgp = wt + ((size_t)e*H2X + INNER + j0 + rA)*KDIM;
  floatx4 aca[4][2], acg[4][2];
  #pragma unroll
  for(int i=0;i<4;i++)
    #pragma unroll
    for(int j=0;j<2;j++){ aca[i][j]=(floatx4){0.f,0.f,0.f,0.f}; acg[i][j]=(floatx4){0.f,0.f,0.f,0.f}; }
  for(int kt=0; kt<KDIM; kt+=32){
    __syncthreads();
    gload16(a0p + kt + c8*8, &sA[wid*512]);
    gload16(a1p + kt + c8*8, &sA[2048 + wid*512]);
    gload16(bap + kt + c8*8, &sBa[wid*512]);
    gload16(bgp + kt + c8*8, &sBg[wid*512]);
    __syncthreads();
    bf16x8 af[4], ba[2], bg[2];
    #pragma unroll
    for(int mi=0;mi<4;mi++) af[mi] = *(const bf16x8*)&sA[(wm*64+mi*16+l15)*32 + quad*8];
    #pragma unroll
    for(int ni=0;ni<2;ni++){
      ba[ni] = *(const bf16x8*)&sBa[(wn*32+ni*16+l15)*32 + quad*8];
      bg[ni] = *(const bf16x8*)&sBg[(wn*32+ni*16+l15)*32 + quad*8];
    }
    #pragma unroll
    for(int mi=0;mi<4;mi++)
      #pragma unroll
      for(int ni=0;ni<2;ni++){
        aca[mi][ni] = __builtin_amdgcn_mfma_f32_16x16x32_bf16(af[mi], ba[ni], aca[mi][ni],0,0,0);
        acg[mi][ni] = __builtin_amdgcn_mfma_f32_16x16x32_bf16(af[mi], bg[ni], acg[mi][ni],0,0,0);
      }
  }
  #pragma unroll
  for(int ni=0;ni<2;ni++){
    int j = j0 + wn*32 + ni*16 + l15;
    float ba_ = bias[e*H2X + j];
    float bg_ = bias[e*H2X + INNER + j];
    #pragma unroll
    for(int mi=0;mi<4;mi++){
      int rl = wm*64 + mi*16 + quad*4;
      #pragma unroll
      for(int r=0;r<4;r++){
        int row = mtile*128 + rl + r;
        if(row < cn){
          float a = aca[mi][ni][r] + ba_;
          float g = acg[mi][ni][r] + bg_;
          out[(size_t)(base+row)*INNER + j] = f2bs(a * g * fsigmoid(g));
        }
      }
    }
  }
}

// ---------------- expert output GEMM -> eo (plain stores) ----------------
__global__ __launch_bounds__(256) void gemm_out_kernel(
    const unsigned short* __restrict__ h2, const unsigned short* __restrict__ w3t,
    const float* __restrict__ be3, const int* __restrict__ cnt, float* __restrict__ eo){
  int e = blockIdx.z;
  int cn = cnt[e];
  int mtile = blockIdx.y;
  if (mtile*128 >= cn) return;
  int base = prefix_cnt(cnt, e);
  int n0 = blockIdx.x*128;
  int tid=threadIdx.x, lane=tid&63, wid=tid>>6, wm=wid&1, wn=wid>>1;
  int l15=lane&15, quad=lane>>4;
  __shared__ alignas(16) unsigned short sA[128*32];
  __shared__ alignas(16) unsigned short sB[128*32];
  int rA = tid>>2, c8 = tid&3;
  int lr0 = mtile*128 + rA, lr1 = lr0+64;
  const unsigned short* a0p = h2 + (size_t)(base + min(lr0, cn-1))*INNER;
  const unsigned short* a1p = h2 + (size_t)(base + min(lr1, cn-1))*INNER;
  const unsigned short* b0p = w3t + ((size_t)e*DIM + n0 + rA)*INNER;
  const unsigned short* b1p = w3t + ((size_t)e*DIM + n0 + 64 + rA)*INNER;
  floatx4 acc[4][4];
  #pragma unroll
  for(int i=0;i<4;i++)
    #pragma unroll
    for(int j=0;j<4;j++) acc[i][j]=(floatx4){0.f,0.f,0.f,0.f};
  for(int kt=0; kt<INNER; kt+=32){
    __syncthreads();
    gload16(a0p + kt + c8*8, &sA[wid*512]);
    gload16(a1p + kt + c8*8, &sA[2048 + wid*512]);
    gload16(b0p + kt + c8*8, &sB[wid*512]);
    gload16(b1p + kt + c8*8, &sB[2048 + wid*512]);
    __syncthreads();
    bf16x8 af[4], bfr[4];
    #pragma unroll
    for(int mi=0;mi<4;mi++) af[mi] = *(const bf16x8*)&sA[(wm*64+mi*16+l15)*32 + quad*8];
    #pragma unroll
    for(int ni=0;ni<4;ni++) bfr[ni] = *(const bf16x8*)&sB[(wn*64+ni*16+l15)*32 + quad*8];
    #pragma unroll
    for(int mi=0;mi<4;mi++)
      #pragma unroll
      for(int ni=0;ni<4;ni++)
        acc[mi][ni] = __builtin_amdgcn_mfma_f32_16x16x32_bf16(af[mi], bfr[ni], acc[mi][ni],0,0,0);
  }
  #pragma unroll
  for(int ni=0;ni<4;ni++){
    int col = n0 + wn*64 + ni*16 + l15;
    float b3 = be3[e*DIM + col];
    #pragma unroll
    for(int mi=0;mi<4;mi++){
      int rl = wm*64 + mi*16 + quad*4;
      #pragma unroll
      for(int r=0;r<4;r++){
        int row = mtile*128 + rl + r;
        if(row < cn){
          eo[(size_t)(base+row)*DIM + col] = acc[mi][ni][r] + b3;
        }
      }
    }
  }
}

// combine: y[n] += w0*eo[p0] + w1*eo[p1]
__global__ __launch_bounds__(384) void combine_kernel(const float* __restrict__ eo,
    const int* __restrict__ inv, const float* __restrict__ rwt, float* __restrict__ y){
  int n = blockIdx.x; int d = threadIdx.x;
  int p0 = inv[2*n], p1 = inv[2*n+1];
  float w0 = rwt[2*n], w1 = rwt[2*n+1];
  size_t o = (size_t)n*DIM + d;
  y[o] += w0*eo[(size_t)p0*DIM+d] + w1*eo[(size_t)p1*DIM+d];
}

// ---------------- senet pooled / gate / final ----------------
__global__ __launch_bounds__(384) void pooled_kernel(const float* __restrict__ x,
    const float* __restrict__ sres, const float* __restrict__ y, float* __restrict__ pooled){
  int b = blockIdx.y, c = blockIdx.x;
  int d = threadIdx.x;
  float sr = sres[d];
  float s=0.f;
  for(int t=c*32;t<c*32+32;t++){
    size_t o=((size_t)b*NT+t)*DIM+d;
    s += x[o]*sr + y[o];
  }
  atomicAdd(&pooled[b*DIM+d], s*(1.f/NT));
}

__global__ __launch_bounds__(128) void gate_kernel(const float* __restrict__ pooled,
    const float* __restrict__ sw1, const float* __restrict__ sb1,
    const float* __restrict__ sw2, const float* __restrict__ sb2, float* __restrict__ gate){
  int b=blockIdx.x; int tid=threadIdx.x;
  __shared__ float sp[DIM];
  __shared__ float sh[SQZ];
  for(int i=tid;i<DIM;i+=128) sp[i]=pooled[b*DIM+i];
  __syncthreads();
  if(tid<SQZ){
    float a=sb1[tid];
    for(int d=0;d<DIM;d++) a += sp[d]*sw1[d*SQZ+tid];
    sh[tid]= a*fsigmoid(a);
  }
  __syncthreads();
  for(int i=tid;i<DIM;i+=128){
    float a=sb2[i];
    #pragma unroll
    for(int j=0;j<SQZ;j++) a += sh[j]*sw2[j*DIM+i];
    gate[b*DIM+i]=fsigmoid(a);
  }
}

__global__ __launch_bounds__(256) void final_kernel(const float* __restrict__ res,
    const float* __restrict__ y, const float* __restrict__ gate, float* __restrict__ out){
  int i4 = blockIdx.x*256+threadIdx.x;
  int d4 = i4 % 96; int row = i4 / 96; int b = row>>10;
  float4 r = *(const float4*)&res[(size_t)i4*4];
  float4 yv = *(const float4*)&y[(size_t)i4*4];
  float4 gv = *(const float4*)&gate[b*DIM + d4*4];
  float4 o;
  o.x=r.x+yv.x*gv.x; o.y=r.y+yv.y*gv.y; o.z=r.z+yv.z*gv.z; o.w=r.w+yv.w*gv.w;
  *(float4*)&out[(size_t)i4*4]=o;
}

extern "C" void kernel_launch(void* const* d_in, const int* in_sizes, int n_in,
                              void* d_out, int out_size, void* d_ws, size_t ws_size,
                              hipStream_t stream) {
  (void)in_sizes; (void)n_in; (void)out_size; (void)ws_size;
  const float* res   = (const float*)d_in[0];
  const float* ln_g  = (const float*)d_in[1];
  const float* ln_b  = (const float*)d_in[2];
  const float* conv_w= (const float*)d_in[3];
  const float* conv_b= (const float*)d_in[4];
  const float* rw1   = (const float*)d_in[5];
  const float* rb1   = (const float*)d_in[6];
  const float* rw2   = (const float*)d_in[7];
  const float* rb2   = (const float*)d_in[8];
  const float* we1   = (const float*)d_in[9];
  const float* be1   = (const float*)d_in[10];
  const float* we2   = (const float*)d_in[11];
  const float* be2   = (const float*)d_in[12];
  const float* we3   = (const float*)d_in[13];
  const float* be3   = (const float*)d_in[14];
  const float* sw1   = (const float*)d_in[15];
  const float* sb1   = (const float*)d_in[16];
  const float* sw2   = (const float*)d_in[17];
  const float* sb2   = (const float*)d_in[18];
  const float* sres  = (const float*)d_in[19];
  float* out = (float*)d_out;

  char* ws = (char*)d_ws;
  size_t off = 0;
  auto alloc = [&](size_t bytes)->void*{ void* p = ws + off; off = (off + bytes + 255) & ~(size_t)255; return p; };
  float*          x     = (float*)alloc((size_t)NN*DIM*4);
  float*          y     = (float*)alloc((size_t)NN*DIM*4);
  float*          eo    = (float*)alloc((size_t)NASSIGN*DIM*4);
  unsigned short* tokb  = (unsigned short*)alloc((size_t)NN*DIM*2);
  unsigned short* tokc  = (unsigned short*)alloc((size_t)NASSIGN*DIM*2);
  unsigned short* g1    = (unsigned short*)alloc((size_t)NN*DIM*2);
  unsigned short* w1t   = (unsigned short*)alloc((size_t)NE*H2X*DIM*2);
  unsigned short* w2t   = (unsigned short*)alloc((size_t)NE*H2X*INNER*2);
  unsigned short* w3t   = (unsigned short*)alloc((size_t)NE*DIM*INNER*2);
  unsigned short* rw1t  = (unsigned short*)alloc((size_t)DIM*DIM*2);
  unsigned short* h1    = (unsigned short*)alloc((size_t)NASSIGN*INNER*2);
  unsigned short* h2b   = (unsigned short*)alloc((size_t)NASSIGN*INNER*2);
  int*            ridx  = (int*)alloc((size_t)NASSIGN*4);
  float*          rwt   = (float*)alloc((size_t)NASSIGN*4);
  int*            perm  = (int*)alloc((size_t)NASSIGN*4);
  float*          pw    = (float*)alloc((size_t)NASSIGN*4);
  int*            inv   = (int*)alloc((size_t)NASSIGN*4);
  int*            cnt   = (int*)alloc(128);      // cnt[0..4], cnt2 = cnt+8
  int*            cnt2  = cnt + 8;
  float*          pooled= (float*)alloc((size_t)NB*DIM*4);
  float*          gate  = (float*)alloc((size_t)NB*DIM*4);
  (void)pw;

  dim3 tb(32,8);
  transpose_cast_kernel<<<dim3(H2X/32, DIM/64, NE), tb, 0, stream>>>(we1, w1t, DIM, H2X);
  transpose_cast_kernel<<<dim3(H2X/32, INNER/64, NE), tb, 0, stream>>>(we2, w2t, INNER, H2X);
  transpose_cast_kernel<<<dim3(DIM/32, INNER/64, NE), tb, 0, stream>>>(we3, w3t, INNER, DIM);
  transpose_cast_kernel<<<dim3(DIM/32, DIM/64, 1), tb, 0, stream>>>(rw1, rw1t, DIM, DIM);

  ln_kernel<<<NN, 128, 0, stream>>>(res, ln_g, ln_b, x);
  conv_kernel<<<dim3(NT/CTT, NB), 384, 0, stream>>>(x, conv_w, conv_b, tokb, y);

  hipMemsetAsync(cnt, 0, 128, stream);
  router_g1_kernel<<<dim3(DIM/128, NN/128), 256, 0, stream>>>(tokb, rw1t, rb1, g1);
  router2_kernel<<<NN/4, 256, 0, stream>>>(g1, rw2, rb2, ridx, rwt, cnt);
  fill_kernel<<<NASSIGN/256, 256, 0, stream>>>(ridx, rwt, cnt, cnt2, perm, pw, inv);
  compact_kernel<<<NASSIGN/8, 768, 0, stream>>>(tokb, perm, tokc);

  gemm_swiglu_kernel<DIM><<<dim3(INNER/64, NN/128, NE), 256, 0, stream>>>(
      tokc, w1t, be1, cnt, h1);
  gemm_swiglu_kernel<INNER><<<dim3(INNER/64, NN/128, NE), 256, 0, stream>>>(
      h1, w2t, be2, cnt, h2b);
  gemm_out_kernel<<<dim3(DIM/128, NN/128, NE), 256, 0, stream>>>(
      h2b, w3t, be3, cnt, eo);
  combine_kernel<<<NN, 384, 0, stream>>>(eo, inv, rwt, y);

  hipMemsetAsync(pooled, 0, (size_t)NB*DIM*4, stream);
  pooled_kernel<<<dim3(32, NB), 384, 0, stream>>>(x, sres, y, pooled);
  gate_kernel<<<NB, 128, 0, stream>>>(pooled, sw1, sb1, sw2, sb2, gate);
  final_kernel<<<(NN*DIM/4)/256, 256, 0, stream>>>(res, y, gate, out);
}

// Round 4
// 611.212 us; speedup vs baseline: 1.1394x; 1.0509x over previous
//
#include <hip/hip_runtime.h>
#include <stdint.h>

#define DIM 384
#define INNER 1536
#define H2X 3072
#define NE 5
#define NB 4
#define NT 1024
#define NN (NB*NT)
#define KSZ 31
#define SQZ 48
#define NASSIGN (NN*2)

typedef float floatx4 __attribute__((ext_vector_type(4)));
typedef __bf16 bf16x8 __attribute__((ext_vector_type(8)));

__device__ __forceinline__ unsigned short f2bs(float f){
  union { float f; uint32_t u; } v; v.f = f;
  uint32_t r = (v.u + 0x7fffu + ((v.u >> 16) & 1u)) >> 16;
  return (unsigned short)r;
}
__device__ __forceinline__ float bs2f(unsigned short s){
  union { uint32_t u; float f; } v; v.u = ((uint32_t)s) << 16; return v.f;
}
__device__ __forceinline__ float fsigmoid(float x){ return 1.f/(1.f+__expf(-x)); }

__device__ __forceinline__ void gload16(const unsigned short* g, unsigned short* l){
  __builtin_amdgcn_global_load_lds(
    reinterpret_cast<const __attribute__((address_space(1))) unsigned int*>(
        reinterpret_cast<uintptr_t>(g)),
    reinterpret_cast<__attribute__((address_space(3))) unsigned int*>(
        (unsigned int)reinterpret_cast<uintptr_t>(l)),
    16, 0, 0);
}

__device__ __forceinline__ int prefix_cnt(const int* __restrict__ cnt, int e){
  int base = 0;
  #pragma unroll
  for(int k=0;k<NE;k++) base += (k<e) ? cnt[k] : 0;
  return base;
}

// ---------------- all weight transposes in ONE dispatch ----------------
// f32 [z][R][C] -> bf16 [z][C][R]; block does 64 rows x 32 cols; threads (32,8)
__device__ __forceinline__ void do_tr(const float* __restrict__ in,
    unsigned short* __restrict__ out, int R, int C, int cx, int cy){
  __shared__ float tile[32][65];
  int c0 = cx*32, r0 = cy*64;
  int tx = threadIdx.x, ty = threadIdx.y;
  #pragma unroll
  for (int i=0;i<8;i++){
    int r = ty + i*8;
    tile[tx][r] = in[(size_t)(r0+r)*C + c0 + tx];
  }
  __syncthreads();
  #pragma unroll
  for (int i=0;i<4;i++){
    int c = ty + i*8;
    uint32_t lo = f2bs(tile[c][2*tx]);
    uint32_t hi = f2bs(tile[c][2*tx+1]);
    *(uint32_t*)&out[(size_t)(c0+c)*R + r0 + 2*tx] = lo | (hi<<16);
  }
}

#define TR_N1 (96*6*5)      // we1: R=384,C=3072
#define TR_N2 (96*24*5)     // we2: R=1536,C=3072
#define TR_N3 (12*24*5)     // we3: R=1536,C=384
#define TR_N4 (12*6)        // rw1: R=384,C=384
__global__ __launch_bounds__(256) void tr_all_kernel(
    const float* __restrict__ we1, unsigned short* __restrict__ w1t,
    const float* __restrict__ we2, unsigned short* __restrict__ w2t,
    const float* __restrict__ we3, unsigned short* __restrict__ w3t,
    const float* __restrict__ rw1, unsigned short* __restrict__ rw1t){
  int bid = blockIdx.x;
  if (bid < TR_N1){
    int z = bid/(96*6), rem = bid%(96*6);
    do_tr(we1 + (size_t)z*384*3072, w1t + (size_t)z*384*3072, 384, 3072, rem%96, rem/96);
  } else if (bid < TR_N1+TR_N2){
    int idx = bid - TR_N1;
    int z = idx/(96*24), rem = idx%(96*24);
    do_tr(we2 + (size_t)z*1536*3072, w2t + (size_t)z*1536*3072, 1536, 3072, rem%96, rem/96);
  } else if (bid < TR_N1+TR_N2+TR_N3){
    int idx = bid - TR_N1 - TR_N2;
    int z = idx/(12*24), rem = idx%(12*24);
    do_tr(we3 + (size_t)z*1536*384, w3t + (size_t)z*1536*384, 1536, 384, rem%12, rem/12);
  } else {
    int idx = bid - TR_N1 - TR_N2 - TR_N3;
    do_tr(rw1, rw1t, 384, 384, idx%12, idx/12);
  }
}

// ---------------- fused LayerNorm + depthwise conv ----------------
// block: 16 owned timesteps + 30 halo; LN computed in-block (halo recomputed)
#define CTT 16
__global__ __launch_bounds__(384) void convln_kernel(const float* __restrict__ res,
    const float* __restrict__ ln_g, const float* __restrict__ ln_b,
    const float* __restrict__ cw, const float* __restrict__ cb,
    float* __restrict__ x, unsigned short* __restrict__ tokb, float* __restrict__ y){
  __shared__ float tile[(CTT+30)*DIM];
  int b = blockIdx.y, t0 = blockIdx.x*CTT;
  int tid = threadIdx.x;
  int w = tid>>6, lane = tid&63;
  float gw[6], bw[6];
  #pragma unroll
  for(int i=0;i<6;i++){ gw[i]=ln_g[i*64+lane]; bw[i]=ln_b[i*64+lane]; }
  for(int r=w; r<CTT+30; r+=6){
    int gt = t0 - 15 + r;
    if(gt>=0 && gt<NT){
      const float* rp = res + ((size_t)b*NT+gt)*DIM;
      float v[6]; float s=0.f;
      #pragma unroll
      for(int i=0;i<6;i++){ v[i]=rp[i*64+lane]; s+=v[i]; }
      #pragma unroll
      for(int o=32;o;o>>=1) s += __shfl_down(s,o);
      s = __shfl(s,0);
      float mean = s*(1.f/DIM);
      float q=0.f;
      #pragma unroll
      for(int i=0;i<6;i++){ v[i]-=mean; q+=v[i]*v[i]; }
      #pragma unroll
      for(int o=32;o;o>>=1) q += __shfl_down(q,o);
      q = __shfl(q,0);
      float rstd = rsqrtf(q*(1.f/DIM) + 1e-5f);
      #pragma unroll
      for(int i=0;i<6;i++) tile[r*DIM+i*64+lane] = v[i]*rstd*gw[i]+bw[i];
    } else {
      #pragma unroll
      for(int i=0;i<6;i++) tile[r*DIM+i*64+lane] = 0.f;
    }
  }
  __syncthreads();
  float cwr[KSZ];
  #pragma unroll
  for(int k=0;k<KSZ;k++) cwr[k] = cw[tid*KSZ+k];
  float bias = cb[tid];
  for(int t=0;t<CTT;t++){
    float acc = bias;
    #pragma unroll
    for(int k=0;k<KSZ;k++) acc += tile[(t+k)*DIM+tid]*cwr[k];
    size_t o = ((size_t)b*NT + t0 + t)*DIM + tid;
    y[o]=acc; tokb[o]=f2bs(acc);
    x[o]=tile[(t+15)*DIM+tid];
  }
}

// ---------------- router GEMM1 (also zeroes cnt/cnt2) ----------------
__global__ __launch_bounds__(256) void router_g1_kernel(const unsigned short* __restrict__ tokb,
    const unsigned short* __restrict__ rw1t, const float* __restrict__ rb1,
    unsigned short* __restrict__ g1, int* __restrict__ cnt){
  int tid = threadIdx.x;
  if(blockIdx.x==0 && blockIdx.y==0 && tid<32) cnt[tid]=0;
  __shared__ alignas(16) unsigned short sA[128*32];
  __shared__ alignas(16) unsigned short sB[128*32];
  int n0 = blockIdx.x*128, m0 = blockIdx.y*128;
  int lane = tid&63, wid = tid>>6, wm = wid&1, wn = wid>>1;
  int l15 = lane&15, quad = lane>>4;
  floatx4 acc[4][4];
  #pragma unroll
  for(int i=0;i<4;i++)
    #pragma unroll
    for(int j=0;j<4;j++) acc[i][j]=(floatx4){0.f,0.f,0.f,0.f};
  int rA = tid>>2, c8 = tid&3;
  const unsigned short* a0p = tokb + (size_t)(m0+rA)*DIM;
  const unsigned short* a1p = tokb + (size_t)(m0+64+rA)*DIM;
  const unsigned short* b0p = rw1t + (size_t)(n0+rA)*DIM;
  const unsigned short* b1p = rw1t + (size_t)(n0+64+rA)*DIM;
  for(int kt=0; kt<DIM; kt+=32){
    __syncthreads();
    gload16(a0p + kt + c8*8, &sA[wid*512]);
    gload16(a1p + kt + c8*8, &sA[2048 + wid*512]);
    gload16(b0p + kt + c8*8, &sB[wid*512]);
    gload16(b1p + kt + c8*8, &sB[2048 + wid*512]);
    __syncthreads();
    bf16x8 af[4], bfr[4];
    #pragma unroll
    for(int mi=0;mi<4;mi++) af[mi] = *(const bf16x8*)&sA[(wm*64+mi*16+l15)*32 + quad*8];
    #pragma unroll
    for(int ni=0;ni<4;ni++) bfr[ni] = *(const bf16x8*)&sB[(wn*64+ni*16+l15)*32 + quad*8];
    #pragma unroll
    for(int mi=0;mi<4;mi++)
      #pragma unroll
      for(int ni=0;ni<4;ni++)
        acc[mi][ni] = __builtin_amdgcn_mfma_f32_16x16x32_bf16(af[mi], bfr[ni], acc[mi][ni],0,0,0);
  }
  #pragma unroll
  for(int ni=0;ni<4;ni++){
    int col = n0 + wn*64 + ni*16 + l15;
    float bias = rb1[col];
    #pragma unroll
    for(int mi=0;mi<4;mi++){
      int rowb = m0 + wm*64 + mi*16 + quad*4;
      #pragma unroll
      for(int r=0;r<4;r++){
        float v = acc[mi][ni][r] + bias;
        g1[(size_t)(rowb+r)*DIM + col] = f2bs(v*fsigmoid(v));
      }
    }
  }
}

// ---------------- router2: scores, top2, softmax weights, counts ----------------
__global__ __launch_bounds__(256) void router2_kernel(const unsigned short* __restrict__ g1,
    const float* __restrict__ rw2, const float* __restrict__ rb2,
    int* __restrict__ ridx, float* __restrict__ rwt, int* __restrict__ cnt){
  int wid = threadIdx.x>>6, lane = threadIdx.x&63;
  int n = blockIdx.x*4 + wid;
  float s[NE]={0.f,0.f,0.f,0.f,0.f};
  #pragma unroll
  for(int i=0;i<6;i++){
    int d = lane + i*64;
    float gv = bs2f(g1[(size_t)n*DIM+d]);
    #pragma unroll
    for(int e=0;e<NE;e++) s[e] += gv * rw2[d*NE+e];
  }
  #pragma unroll
  for(int e=0;e<NE;e++)
    #pragma unroll
    for(int o=32;o;o>>=1) s[e] += __shfl_down(s[e],o);
  if(lane==0){
    float r[NE];
    #pragma unroll
    for(int e=0;e<NE;e++) r[e]=s[e]+rb2[e];
    int e0=0;
    for(int e=1;e<NE;e++) if(r[e]>r[e0]) e0=e;
    int e1=-1;
    for(int e=0;e<NE;e++){ if(e==e0) continue; if(e1<0||r[e]>r[e1]) e1=e; }
    float w0 = 1.f/(1.f+__expf(r[e1]-r[e0]));
    ridx[2*n]=e0; ridx[2*n+1]=e1;
    rwt[2*n]=w0; rwt[2*n+1]=1.f-w0;
    atomicAdd(&cnt[e0],1); atomicAdd(&cnt[e1],1);
  }
}

// ---------------- fill positions + compact token rows + zero pooled ----------------
__global__ __launch_bounds__(256) void fillcompact_kernel(const int* __restrict__ ridx,
    const int* __restrict__ cnt, int* __restrict__ cnt2,
    int* __restrict__ inv, const unsigned short* __restrict__ tokb,
    unsigned short* __restrict__ tokc, float* __restrict__ pooled){
  __shared__ int sSrc[256], sPos[256];
  int tid = threadIdx.x;
  if(blockIdx.x==0){
    for(int i=tid;i<NB*DIM;i+=256) pooled[i]=0.f;
  }
  int i = blockIdx.x*256 + tid;
  int e = ridx[i];
  int base = prefix_cnt(cnt, e);
  int pos = base + atomicAdd(&cnt2[e],1);
  inv[i] = pos;
  sSrc[tid] = i>>1;
  sPos[tid] = pos;
  __syncthreads();
  int w = tid>>6, lane = tid&63;
  for(int j=0;j<64;j++){
    int idx = w*64+j;
    int src = sSrc[idx], dst = sPos[idx];
    if(lane<48){
      const uint4* s = (const uint4*)&tokb[(size_t)src*DIM];
      uint4* d = (uint4*)&tokc[(size_t)dst*DIM];
      d[lane] = s[lane];
    }
  }
}

// ---------------- expert GEMM with fused SwiGLU (contiguous A) ----------------
template<int KDIM>
__global__ __launch_bounds__(256) void gemm_swiglu_kernel(
    const unsigned short* __restrict__ A,
    const unsigned short* __restrict__ wt, const float* __restrict__ bias,
    const int* __restrict__ cnt, unsigned short* __restrict__ out){
  int e = blockIdx.z;
  int cn = cnt[e];
  int mtile = blockIdx.y;
  if (mtile*128 >= cn) return;
  int base = prefix_cnt(cnt, e);
  int j0 = blockIdx.x*64;
  int tid=threadIdx.x, lane=tid&63, wid=tid>>6, wm=wid&1, wn=wid>>1;
  int l15=lane&15, quad=lane>>4;
  __shared__ alignas(16) unsigned short sA[128*32];
  __shared__ alignas(16) unsigned short sBa[64*32];
  __shared__ alignas(16) unsigned short sBg[64*32];
  int rA = tid>>2, c8 = tid&3;
  int lr0 = mtile*128 + rA, lr1 = lr0+64;
  const unsigned short* a0p = A + (size_t)(base + min(lr0, cn-1))*KDIM;
  const unsigned short* a1p = A + (size_t)(base + min(lr1, cn-1))*KDIM;
  const unsigned short* bap = wt + ((size_t)e*H2X + j0 + rA)*KDIM;
  const unsigned short* bgp = wt + ((size_t)e*H2X + INNER + j0 + rA)*KDIM;
  floatx4 aca[4][2], acg[4][2];
  #pragma unroll
  for(int i=0;i<4;i++)
    #pragma unroll
    for(int j=0;j<2;j++){ aca[i][j]=(floatx4){0.f,0.f,0.f,0.f}; acg[i][j]=(floatx4){0.f,0.f,0.f,0.f}; }
  for(int kt=0; kt<KDIM; kt+=32){
    __syncthreads();
    gload16(a0p + kt + c8*8, &sA[wid*512]);
    gload16(a1p + kt + c8*8, &sA[2048 + wid*512]);
    gload16(bap + kt + c8*8, &sBa[wid*512]);
    gload16(bgp + kt + c8*8, &sBg[wid*512]);
    __syncthreads();
    bf16x8 af[4], ba[2], bg[2];
    #pragma unroll
    for(int mi=0;mi<4;mi++) af[mi] = *(const bf16x8*)&sA[(wm*64+mi*16+l15)*32 + quad*8];
    #pragma unroll
    for(int ni=0;ni<2;ni++){
      ba[ni] = *(const bf16x8*)&sBa[(wn*32+ni*16+l15)*32 + quad*8];
      bg[ni] = *(const bf16x8*)&sBg[(wn*32+ni*16+l15)*32 + quad*8];
    }
    #pragma unroll
    for(int mi=0;mi<4;mi++)
      #pragma unroll
      for(int ni=0;ni<2;ni++){
        aca[mi][ni] = __builtin_amdgcn_mfma_f32_16x16x32_bf16(af[mi], ba[ni], aca[mi][ni],0,0,0);
        acg[mi][ni] = __builtin_amdgcn_mfma_f32_16x16x32_bf16(af[mi], bg[ni], acg[mi][ni],0,0,0);
      }
  }
  #pragma unroll
  for(int ni=0;ni<2;ni++){
    int j = j0 + wn*32 + ni*16 + l15;
    float ba_ = bias[e*H2X + j];
    float bg_ = bias[e*H2X + INNER + j];
    #pragma unroll
    for(int mi=0;mi<4;mi++){
      int rl = wm*64 + mi*16 + quad*4;
      #pragma unroll
      for(int r=0;r<4;r++){
        int row = mtile*128 + rl + r;
        if(row < cn){
          float a = aca[mi][ni][r] + ba_;
          float g = acg[mi][ni][r] + bg_;
          out[(size_t)(base+row)*INNER + j] = f2bs(a * g * fsigmoid(g));
        }
      }
    }
  }
}

// ---------------- expert output GEMM, split-K=2 -> two eo slabs ----------------
__global__ __launch_bounds__(256) void gemm_out_kernel(
    const unsigned short* __restrict__ h2, const unsigned short* __restrict__ w3t,
    const float* __restrict__ be3, const int* __restrict__ cnt, float* __restrict__ eo){
  int e = blockIdx.z;
  int cn = cnt[e];
  int mtile = blockIdx.y;
  if (mtile*128 >= cn) return;
  int base = prefix_cnt(cnt, e);
  int jt = blockIdx.x % 3, kh = blockIdx.x / 3;
  int n0 = jt*128;
  int koff = kh*768;
  float* eos = eo + (size_t)kh*NASSIGN*DIM;
  int tid=threadIdx.x, lane=tid&63, wid=tid>>6, wm=wid&1, wn=wid>>1;
  int l15=lane&15, quad=lane>>4;
  __shared__ alignas(16) unsigned short sA[128*32];
  __shared__ alignas(16) unsigned short sB[128*32];
  int rA = tid>>2, c8 = tid&3;
  int lr0 = mtile*128 + rA, lr1 = lr0+64;
  const unsigned short* a0p = h2 + (size_t)(base + min(lr0, cn-1))*INNER + koff;
  const unsigned short* a1p = h2 + (size_t)(base + min(lr1, cn-1))*INNER + koff;
  const unsigned short* b0p = w3t + ((size_t)e*DIM + n0 + rA)*INNER + koff;
  const unsigned short* b1p = w3t + ((size_t)e*DIM + n0 + 64 + rA)*INNER + koff;
  floatx4 acc[4][4];
  #pragma unroll
  for(int i=0;i<4;i++)
    #pragma unroll
    for(int j=0;j<4;j++) acc[i][j]=(floatx4){0.f,0.f,0.f,0.f};
  for(int kt=0; kt<768; kt+=32){
    __syncthreads();
    gload16(a0p + kt + c8*8, &sA[wid*512]);
    gload16(a1p + kt + c8*8, &sA[2048 + wid*512]);
    gload16(b0p + kt + c8*8, &sB[wid*512]);
    gload16(b1p + kt + c8*8, &sB[2048 + wid*512]);
    __syncthreads();
    bf16x8 af[4], bfr[4];
    #pragma unroll
    for(int mi=0;mi<4;mi++) af[mi] = *(const bf16x8*)&sA[(wm*64+mi*16+l15)*32 + quad*8];
    #pragma unroll
    for(int ni=0;ni<4;ni++) bfr[ni] = *(const bf16x8*)&sB[(wn*64+ni*16+l15)*32 + quad*8];
    #pragma unroll
    for(int mi=0;mi<4;mi++)
      #pragma unroll
      for(int ni=0;ni<4;ni++)
        acc[mi][ni] = __builtin_amdgcn_mfma_f32_16x16x32_bf16(af[mi], bfr[ni], acc[mi][ni],0,0,0);
  }
  #pragma unroll
  for(int ni=0;ni<4;ni++){
    int col = n0 + wn*64 + ni*16 + l15;
    float b3 = (kh==0) ? be3[e*DIM + col] : 0.f;
    #pragma unroll
    for(int mi=0;mi<4;mi++){
      int rl = wm*64 + mi*16 + quad*4;
      #pragma unroll
      for(int r=0;r<4;r++){
        int row = mtile*128 + rl + r;
        if(row < cn){
          eos[(size_t)(base+row)*DIM + col] = acc[mi][ni][r] + b3;
        }
      }
    }
  }
}

// ---------------- combine expert outputs + pooled accumulation ----------------
__global__ __launch_bounds__(384) void combine_pooled_kernel(const float* __restrict__ eo,
    const int* __restrict__ inv, const float* __restrict__ rwt,
    const float* __restrict__ x, const float* __restrict__ sres,
    float* __restrict__ y, float* __restrict__ pooled){
  int b = blockIdx.y, t0 = blockIdx.x*8;
  int d = threadIdx.x;
  const float* eo1 = eo + (size_t)NASSIGN*DIM;
  float sr = sres[d];
  float acc = 0.f;
  for(int t=0;t<8;t++){
    int n = b*NT + t0 + t;
    int p0 = inv[2*n], p1 = inv[2*n+1];
    float w0 = rwt[2*n], w1 = rwt[2*n+1];
    size_t o = (size_t)n*DIM + d;
    float yv = y[o] + w0*(eo[(size_t)p0*DIM+d] + eo1[(size_t)p0*DIM+d])
                    + w1*(eo[(size_t)p1*DIM+d] + eo1[(size_t)p1*DIM+d]);
    y[o] = yv;
    acc += x[o]*sr + yv;
  }
  atomicAdd(&pooled[b*DIM+d], acc*(1.f/NT));
}

// ---------------- fused gate + final ----------------
__global__ __launch_bounds__(384) void gatefinal_kernel(const float* __restrict__ pooled,
    const float* __restrict__ sw1, const float* __restrict__ sb1,
    const float* __restrict__ sw2, const float* __restrict__ sb2,
    const float* __restrict__ res, const float* __restrict__ y, float* __restrict__ out){
  int b = blockIdx.y, t0 = blockIdx.x*8;
  int d = threadIdx.x;
  __shared__ float sp[DIM];
  __shared__ float sh[SQZ];
  sp[d] = pooled[b*DIM+d];
  __syncthreads();
  if(d<SQZ){
    float a = sb1[d];
    for(int k=0;k<DIM;k++) a += sp[k]*sw1[k*SQZ+d];
    sh[d] = a*fsigmoid(a);
  }
  __syncthreads();
  float a = sb2[d];
  #pragma unroll
  for(int j=0;j<SQZ;j++) a += sh[j]*sw2[j*DIM+d];
  float g = fsigmoid(a);
  for(int t=0;t<8;t++){
    size_t o = ((size_t)b*NT + t0 + t)*DIM + d;
    out[o] = res[o] + y[o]*g;
  }
}

extern "C" void kernel_launch(void* const* d_in, const int* in_sizes, int n_in,
                              void* d_out, int out_size, void* d_ws, size_t ws_size,
                              hipStream_t stream) {
  (void)in_sizes; (void)n_in; (void)out_size; (void)ws_size;
  const float* res   = (const float*)d_in[0];
  const float* ln_g  = (const float*)d_in[1];
  const float* ln_b  = (const float*)d_in[2];
  const float* conv_w= (const float*)d_in[3];
  const float* conv_b= (const float*)d_in[4];
  const float* rw1   = (const float*)d_in[5];
  const float* rb1   = (const float*)d_in[6];
  const float* rw2   = (const float*)d_in[7];
  const float* rb2   = (const float*)d_in[8];
  const float* we1   = (const float*)d_in[9];
  const float* be1   = (const float*)d_in[10];
  const float* we2   = (const float*)d_in[11];
  const float* be2   = (const float*)d_in[12];
  const float* we3   = (const float*)d_in[13];
  const float* be3   = (const float*)d_in[14];
  const float* sw1   = (const float*)d_in[15];
  const float* sb1   = (const float*)d_in[16];
  const float* sw2   = (const float*)d_in[17];
  const float* sb2   = (const float*)d_in[18];
  const float* sres  = (const float*)d_in[19];
  float* out = (float*)d_out;

  char* ws = (char*)d_ws;
  size_t off = 0;
  auto alloc = [&](size_t bytes)->void*{ void* p = ws + off; off = (off + bytes + 255) & ~(size_t)255; return p; };
  float*          x     = (float*)alloc((size_t)NN*DIM*4);
  float*          y     = (float*)alloc((size_t)NN*DIM*4);
  float*          eo    = (float*)alloc((size_t)2*NASSIGN*DIM*4);
  unsigned short* tokb  = (unsigned short*)alloc((size_t)NN*DIM*2);
  unsigned short* tokc  = (unsigned short*)alloc((size_t)NASSIGN*DIM*2);
  unsigned short* g1    = (unsigned short*)alloc((size_t)NN*DIM*2);
  unsigned short* w1t   = (unsigned short*)alloc((size_t)NE*H2X*DIM*2);
  unsigned short* w2t   = (unsigned short*)alloc((size_t)NE*H2X*INNER*2);
  unsigned short* w3t   = (unsigned short*)alloc((size_t)NE*DIM*INNER*2);
  unsigned short* rw1t  = (unsigned short*)alloc((size_t)DIM*DIM*2);
  unsigned short* h1    = (unsigned short*)alloc((size_t)NASSIGN*INNER*2);
  unsigned short* h2b   = (unsigned short*)alloc((size_t)NASSIGN*INNER*2);
  int*            ridx  = (int*)alloc((size_t)NASSIGN*4);
  float*          rwt   = (float*)alloc((size_t)NASSIGN*4);
  int*            inv   = (int*)alloc((size_t)NASSIGN*4);
  int*            cnt   = (int*)alloc(128);
  int*            cnt2  = cnt + 8;
  float*          pooled= (float*)alloc((size_t)NB*DIM*4);

  tr_all_kernel<<<TR_N1+TR_N2+TR_N3+TR_N4, dim3(32,8), 0, stream>>>(
      we1, w1t, we2, w2t, we3, w3t, rw1, rw1t);
  convln_kernel<<<dim3(NT/CTT, NB), 384, 0, stream>>>(
      res, ln_g, ln_b, conv_w, conv_b, x, tokb, y);
  router_g1_kernel<<<dim3(DIM/128, NN/128), 256, 0, stream>>>(tokb, rw1t, rb1, g1, cnt);
  router2_kernel<<<NN/4, 256, 0, stream>>>(g1, rw2, rb2, ridx, rwt, cnt);
  fillcompact_kernel<<<NASSIGN/256, 256, 0, stream>>>(ridx, cnt, cnt2, inv, tokb, tokc, pooled);

  gemm_swiglu_kernel<DIM><<<dim3(INNER/64, NN/128, NE), 256, 0, stream>>>(
      tokc, w1t, be1, cnt, h1);
  gemm_swiglu_kernel<INNER><<<dim3(INNER/64, NN/128, NE), 256, 0, stream>>>(
      h1, w2t, be2, cnt, h2b);
  gemm_out_kernel<<<dim3(6, NN/128, NE), 256, 0, stream>>>(
      h2b, w3t, be3, cnt, eo);
  combine_pooled_kernel<<<dim3(NT/8, NB), 384, 0, stream>>>(
      eo, inv, rwt, x, sres, y, pooled);
  gatefinal_kernel<<<dim3(NT/8, NB), 384, 0, stream>>>(
      pooled, sw1, sb1, sw2, sb2, res, y, out);
}

// Round 5
// 594.633 us; speedup vs baseline: 1.1712x; 1.0279x over previous
//
#include <hip/hip_runtime.h>
#include <stdint.h>

#define DIM 384
#define INNER 1536
#define H2X 3072
#define NE 5
#define NB 4
#define NT 1024
#define NN (NB*NT)
#define KSZ 31
#define SQZ 48
#define NASSIGN (NN*2)

typedef float floatx4 __attribute__((ext_vector_type(4)));
typedef __bf16 bf16x8 __attribute__((ext_vector_type(8)));

__device__ __forceinline__ unsigned short f2bs(float f){
  union { float f; uint32_t u; } v; v.f = f;
  uint32_t r = (v.u + 0x7fffu + ((v.u >> 16) & 1u)) >> 16;
  return (unsigned short)r;
}
__device__ __forceinline__ float bs2f(unsigned short s){
  union { uint32_t u; float f; } v; v.u = ((uint32_t)s) << 16; return v.f;
}
__device__ __forceinline__ float fsigmoid(float x){ return 1.f/(1.f+__expf(-x)); }

// pack2 fp8(e4m3) from 2 floats into low/high half of a u32
__device__ __forceinline__ uint32_t pk2_lo(float a, float b, uint32_t old){
  return __builtin_amdgcn_cvt_pk_fp8_f32(a, b, old, false);
}
__device__ __forceinline__ uint32_t pk2_hi(float a, float b, uint32_t old){
  return __builtin_amdgcn_cvt_pk_fp8_f32(a, b, old, true);
}
__device__ __forceinline__ uint8_t f2fp8(float a){
  return (uint8_t)__builtin_amdgcn_cvt_pk_fp8_f32(a, 0.f, 0u, false);
}

__device__ __forceinline__ void gload16(const void* g, void* l){
  __builtin_amdgcn_global_load_lds(
    reinterpret_cast<const __attribute__((address_space(1))) unsigned int*>(
        reinterpret_cast<uintptr_t>(g)),
    reinterpret_cast<__attribute__((address_space(3))) unsigned int*>(
        (unsigned int)reinterpret_cast<uintptr_t>(l)),
    16, 0, 0);
}

__device__ __forceinline__ int prefix_cnt(const int* __restrict__ cnt, int e){
  int base = 0;
  #pragma unroll
  for(int k=0;k<NE;k++) base += (k<e) ? cnt[k] : 0;
  return base;
}

#define WSCALE 8.f

// ---------------- weight transposes (one dispatch) ----------------
// bf16 variant: f32 [R][C] -> bf16 [C][R]
__device__ __forceinline__ void do_tr_bf16(const float* __restrict__ in,
    unsigned short* __restrict__ out, int R, int C, int cx, int cy){
  __shared__ float tile[32][65];
  int c0 = cx*32, r0 = cy*64;
  int tx = threadIdx.x, ty = threadIdx.y;
  #pragma unroll
  for (int i=0;i<8;i++){
    int r = ty + i*8;
    tile[tx][r] = in[(size_t)(r0+r)*C + c0 + tx];
  }
  __syncthreads();
  #pragma unroll
  for (int i=0;i<4;i++){
    int c = ty + i*8;
    uint32_t lo = f2bs(tile[c][2*tx]);
    uint32_t hi = f2bs(tile[c][2*tx+1]);
    *(uint32_t*)&out[(size_t)(c0+c)*R + r0 + 2*tx] = lo | (hi<<16);
  }
}
// fp8 variant: f32 [R][C] -> fp8 [C][R], scaled by WSCALE
__device__ __forceinline__ void do_tr_fp8(const float* __restrict__ in,
    uint8_t* __restrict__ out, int R, int C, int cx, int cy){
  __shared__ float tile[32][65];
  int c0 = cx*32, r0 = cy*64;
  int tx = threadIdx.x, ty = threadIdx.y;
  #pragma unroll
  for (int i=0;i<8;i++){
    int r = ty + i*8;
    tile[tx][r] = in[(size_t)(r0+r)*C + c0 + tx];
  }
  __syncthreads();
  #pragma unroll
  for (int i=0;i<4;i++){
    int c = ty + i*8;
    uint32_t v = pk2_lo(tile[c][2*tx]*WSCALE, tile[c][2*tx+1]*WSCALE, 0u);
    *(unsigned short*)&out[(size_t)(c0+c)*R + r0 + 2*tx] = (unsigned short)(v & 0xffffu);
  }
}

#define TR_N1 (96*6*5)      // we1: R=384,C=3072
#define TR_N2 (96*24*5)     // we2: R=1536,C=3072
#define TR_N3 (12*24*5)     // we3: R=1536,C=384
#define TR_N4 (12*6)        // rw1: R=384,C=384 (bf16)
__global__ __launch_bounds__(256) void tr_all_kernel(
    const float* __restrict__ we1, uint8_t* __restrict__ w1t,
    const float* __restrict__ we2, uint8_t* __restrict__ w2t,
    const float* __restrict__ we3, uint8_t* __restrict__ w3t,
    const float* __restrict__ rw1, unsigned short* __restrict__ rw1t){
  int bid = blockIdx.x;
  if (bid < TR_N1){
    int z = bid/(96*6), rem = bid%(96*6);
    do_tr_fp8(we1 + (size_t)z*384*3072, w1t + (size_t)z*384*3072, 384, 3072, rem%96, rem/96);
  } else if (bid < TR_N1+TR_N2){
    int idx = bid - TR_N1;
    int z = idx/(96*24), rem = idx%(96*24);
    do_tr_fp8(we2 + (size_t)z*1536*3072, w2t + (size_t)z*1536*3072, 1536, 3072, rem%96, rem/96);
  } else if (bid < TR_N1+TR_N2+TR_N3){
    int idx = bid - TR_N1 - TR_N2;
    int z = idx/(12*24), rem = idx%(12*24);
    do_tr_fp8(we3 + (size_t)z*1536*384, w3t + (size_t)z*1536*384, 1536, 384, rem%12, rem/12);
  } else {
    int idx = bid - TR_N1 - TR_N2 - TR_N3;
    do_tr_bf16(rw1, rw1t, 384, 384, idx%12, idx/12);
  }
}

// ---------------- fused LayerNorm + depthwise conv ----------------
#define CTT 16
__global__ __launch_bounds__(384) void convln_kernel(const float* __restrict__ res,
    const float* __restrict__ ln_g, const float* __restrict__ ln_b,
    const float* __restrict__ cw, const float* __restrict__ cb,
    float* __restrict__ x, unsigned short* __restrict__ tokb, float* __restrict__ y){
  __shared__ float tile[(CTT+30)*DIM];
  int b = blockIdx.y, t0 = blockIdx.x*CTT;
  int tid = threadIdx.x;
  int w = tid>>6, lane = tid&63;
  float gw[6], bw[6];
  #pragma unroll
  for(int i=0;i<6;i++){ gw[i]=ln_g[i*64+lane]; bw[i]=ln_b[i*64+lane]; }
  for(int r=w; r<CTT+30; r+=6){
    int gt = t0 - 15 + r;
    if(gt>=0 && gt<NT){
      const float* rp = res + ((size_t)b*NT+gt)*DIM;
      float v[6]; float s=0.f;
      #pragma unroll
      for(int i=0;i<6;i++){ v[i]=rp[i*64+lane]; s+=v[i]; }
      #pragma unroll
      for(int o=32;o;o>>=1) s += __shfl_down(s,o);
      s = __shfl(s,0);
      float mean = s*(1.f/DIM);
      float q=0.f;
      #pragma unroll
      for(int i=0;i<6;i++){ v[i]-=mean; q+=v[i]*v[i]; }
      #pragma unroll
      for(int o=32;o;o>>=1) q += __shfl_down(q,o);
      q = __shfl(q,0);
      float rstd = rsqrtf(q*(1.f/DIM) + 1e-5f);
      #pragma unroll
      for(int i=0;i<6;i++) tile[r*DIM+i*64+lane] = v[i]*rstd*gw[i]+bw[i];
    } else {
      #pragma unroll
      for(int i=0;i<6;i++) tile[r*DIM+i*64+lane] = 0.f;
    }
  }
  __syncthreads();
  float cwr[KSZ];
  #pragma unroll
  for(int k=0;k<KSZ;k++) cwr[k] = cw[tid*KSZ+k];
  float bias = cb[tid];
  for(int t=0;t<CTT;t++){
    float acc = bias;
    #pragma unroll
    for(int k=0;k<KSZ;k++) acc += tile[(t+k)*DIM+tid]*cwr[k];
    size_t o = ((size_t)b*NT + t0 + t)*DIM + tid;
    y[o]=acc; tokb[o]=f2bs(acc);
    x[o]=tile[(t+15)*DIM+tid];
  }
}

// ---------------- router GEMM1 (bf16; also zeroes cnt/cnt2) ----------------
__global__ __launch_bounds__(256) void router_g1_kernel(const unsigned short* __restrict__ tokb,
    const unsigned short* __restrict__ rw1t, const float* __restrict__ rb1,
    unsigned short* __restrict__ g1, int* __restrict__ cnt){
  int tid = threadIdx.x;
  if(blockIdx.x==0 && blockIdx.y==0 && tid<32) cnt[tid]=0;
  __shared__ alignas(16) unsigned short sA[128*32];
  __shared__ alignas(16) unsigned short sB[128*32];
  int n0 = blockIdx.x*128, m0 = blockIdx.y*128;
  int lane = tid&63, wid = tid>>6, wm = wid&1, wn = wid>>1;
  int l15 = lane&15, quad = lane>>4;
  floatx4 acc[4][4];
  #pragma unroll
  for(int i=0;i<4;i++)
    #pragma unroll
    for(int j=0;j<4;j++) acc[i][j]=(floatx4){0.f,0.f,0.f,0.f};
  int rA = tid>>2, c8 = tid&3;
  const unsigned short* a0p = tokb + (size_t)(m0+rA)*DIM;
  const unsigned short* a1p = tokb + (size_t)(m0+64+rA)*DIM;
  const unsigned short* b0p = rw1t + (size_t)(n0+rA)*DIM;
  const unsigned short* b1p = rw1t + (size_t)(n0+64+rA)*DIM;
  for(int kt=0; kt<DIM; kt+=32){
    __syncthreads();
    gload16(a0p + kt + c8*8, &sA[wid*512]);
    gload16(a1p + kt + c8*8, &sA[2048 + wid*512]);
    gload16(b0p + kt + c8*8, &sB[wid*512]);
    gload16(b1p + kt + c8*8, &sB[2048 + wid*512]);
    __syncthreads();
    bf16x8 af[4], bfr[4];
    #pragma unroll
    for(int mi=0;mi<4;mi++) af[mi] = *(const bf16x8*)&sA[(wm*64+mi*16+l15)*32 + quad*8];
    #pragma unroll
    for(int ni=0;ni<4;ni++) bfr[ni] = *(const bf16x8*)&sB[(wn*64+ni*16+l15)*32 + quad*8];
    #pragma unroll
    for(int mi=0;mi<4;mi++)
      #pragma unroll
      for(int ni=0;ni<4;ni++)
        acc[mi][ni] = __builtin_amdgcn_mfma_f32_16x16x32_bf16(af[mi], bfr[ni], acc[mi][ni],0,0,0);
  }
  #pragma unroll
  for(int ni=0;ni<4;ni++){
    int col = n0 + wn*64 + ni*16 + l15;
    float bias = rb1[col];
    #pragma unroll
    for(int mi=0;mi<4;mi++){
      int rowb = m0 + wm*64 + mi*16 + quad*4;
      #pragma unroll
      for(int r=0;r<4;r++){
        float v = acc[mi][ni][r] + bias;
        g1[(size_t)(rowb+r)*DIM + col] = f2bs(v*fsigmoid(v));
      }
    }
  }
}

// ---------------- router2 ----------------
__global__ __launch_bounds__(256) void router2_kernel(const unsigned short* __restrict__ g1,
    const float* __restrict__ rw2, const float* __restrict__ rb2,
    int* __restrict__ ridx, float* __restrict__ rwt, int* __restrict__ cnt){
  int wid = threadIdx.x>>6, lane = threadIdx.x&63;
  int n = blockIdx.x*4 + wid;
  float s[NE]={0.f,0.f,0.f,0.f,0.f};
  #pragma unroll
  for(int i=0;i<6;i++){
    int d = lane + i*64;
    float gv = bs2f(g1[(size_t)n*DIM+d]);
    #pragma unroll
    for(int e=0;e<NE;e++) s[e] += gv * rw2[d*NE+e];
  }
  #pragma unroll
  for(int e=0;e<NE;e++)
    #pragma unroll
    for(int o=32;o;o>>=1) s[e] += __shfl_down(s[e],o);
  if(lane==0){
    float r[NE];
    #pragma unroll
    for(int e=0;e<NE;e++) r[e]=s[e]+rb2[e];
    int e0=0;
    for(int e=1;e<NE;e++) if(r[e]>r[e0]) e0=e;
    int e1=-1;
    for(int e=0;e<NE;e++){ if(e==e0) continue; if(e1<0||r[e]>r[e1]) e1=e; }
    float w0 = 1.f/(1.f+__expf(r[e1]-r[e0]));
    ridx[2*n]=e0; ridx[2*n+1]=e1;
    rwt[2*n]=w0; rwt[2*n+1]=1.f-w0;
    atomicAdd(&cnt[e0],1); atomicAdd(&cnt[e1],1);
  }
}

// ---------------- fill positions + compact tokens to fp8 (x8) + zero pooled ----------------
__global__ __launch_bounds__(256) void fillcompact_kernel(const int* __restrict__ ridx,
    const int* __restrict__ cnt, int* __restrict__ cnt2,
    int* __restrict__ inv, const unsigned short* __restrict__ tokb,
    uint8_t* __restrict__ tokc, float* __restrict__ pooled){
  __shared__ int sSrc[256], sPos[256];
  int tid = threadIdx.x;
  if(blockIdx.x==0){
    for(int i=tid;i<NB*DIM;i+=256) pooled[i]=0.f;
  }
  int i = blockIdx.x*256 + tid;
  int e = ridx[i];
  int base = prefix_cnt(cnt, e);
  int pos = base + atomicAdd(&cnt2[e],1);
  inv[i] = pos;
  sSrc[tid] = i>>1;
  sPos[tid] = pos;
  __syncthreads();
  int w = tid>>6, lane = tid&63;
  for(int j=0;j<64;j++){
    int idx = w*64+j;
    int src = sSrc[idx], dst = sPos[idx];
    if(lane<48){
      uint4 sv = ((const uint4*)&tokb[(size_t)src*DIM])[lane];
      float f0=bs2f(sv.x&0xffff)*WSCALE, f1=bs2f(sv.x>>16)*WSCALE;
      float f2=bs2f(sv.y&0xffff)*WSCALE, f3=bs2f(sv.y>>16)*WSCALE;
      float f4=bs2f(sv.z&0xffff)*WSCALE, f5=bs2f(sv.z>>16)*WSCALE;
      float f6=bs2f(sv.w&0xffff)*WSCALE, f7=bs2f(sv.w>>16)*WSCALE;
      uint32_t lo = pk2_hi(f2,f3, pk2_lo(f0,f1,0u));
      uint32_t hi = pk2_hi(f6,f7, pk2_lo(f4,f5,0u));
      uint2 pv; pv.x = lo; pv.y = hi;
      ((uint2*)&tokc[(size_t)dst*DIM])[lane] = pv;
    }
  }
}

// ---------------- fp8 expert GEMM + fused SwiGLU (shared impl) ----------------
// A: fp8 rows [*, KDIM] (scaled), wt: fp8 [e][H2X][KDIM] (scaled x8)
// acc*inv_scale = true pre-activation; out stored as fp8( swiglu * out_scale )
template<int KDIM>
__device__ __forceinline__ void gemm_swiglu_impl(
    const uint8_t* __restrict__ A,
    const uint8_t* __restrict__ wt, const float* __restrict__ bias,
    const int* __restrict__ cnt, uint8_t* __restrict__ out,
    float inv_scale, float out_scale){
  int e = blockIdx.z;
  int cn = cnt[e];
  int mtile = blockIdx.y;
  if (mtile*128 >= cn) return;
  int base = prefix_cnt(cnt, e);
  int j0 = blockIdx.x*64;
  int tid=threadIdx.x, lane=tid&63, wid=tid>>6, wm=wid&1, wn=wid>>1;
  int l15=lane&15, quad=lane>>4;
  __shared__ alignas(16) uint8_t sA[128*64];
  __shared__ alignas(16) uint8_t sBa[64*64];
  __shared__ alignas(16) uint8_t sBg[64*64];
  int rA = tid>>2;
  int scc = ((tid&3)*16) ^ (((tid>>2)&3)*16);   // swizzled global byte offset
  int lr0 = mtile*128 + rA, lr1 = lr0+64;
  const uint8_t* a0p = A + (size_t)(base + min(lr0, cn-1))*KDIM;
  const uint8_t* a1p = A + (size_t)(base + min(lr1, cn-1))*KDIM;
  const uint8_t* bap = wt + ((size_t)e*H2X + j0 + rA)*KDIM;
  const uint8_t* bgp = wt + ((size_t)e*H2X + INNER + j0 + rA)*KDIM;
  floatx4 aca[4][2], acg[4][2];
  #pragma unroll
  for(int i=0;i<4;i++)
    #pragma unroll
    for(int j=0;j<2;j++){ aca[i][j]=(floatx4){0.f,0.f,0.f,0.f}; acg[i][j]=(floatx4){0.f,0.f,0.f,0.f}; }
  int swz = (l15&3)*16;
  for(int kt=0; kt<KDIM; kt+=64){
    __syncthreads();
    gload16(a0p + kt + scc, &sA[wid*1024]);
    gload16(a1p + kt + scc, &sA[4096 + wid*1024]);
    gload16(bap + kt + scc, &sBa[wid*1024]);
    gload16(bgp + kt + scc, &sBg[wid*1024]);
    __syncthreads();
    #pragma unroll
    for(int s=0;s<2;s++){
      int kb = (s*32 + quad*8) ^ swz;
      long af[4], ba[2], bg[2];
      #pragma unroll
      for(int mi=0;mi<4;mi++) af[mi] = *(const long*)&sA[(wm*64+mi*16+l15)*64 + kb];
      #pragma unroll
      for(int ni=0;ni<2;ni++){
        ba[ni] = *(const long*)&sBa[(wn*32+ni*16+l15)*64 + kb];
        bg[ni] = *(const long*)&sBg[(wn*32+ni*16+l15)*64 + kb];
      }
      #pragma unroll
      for(int mi=0;mi<4;mi++)
        #pragma unroll
        for(int ni=0;ni<2;ni++){
          aca[mi][ni] = __builtin_amdgcn_mfma_f32_16x16x32_fp8_fp8(af[mi], ba[ni], aca[mi][ni],0,0,0);
          acg[mi][ni] = __builtin_amdgcn_mfma_f32_16x16x32_fp8_fp8(af[mi], bg[ni], acg[mi][ni],0,0,0);
        }
    }
  }
  #pragma unroll
  for(int ni=0;ni<2;ni++){
    int j = j0 + wn*32 + ni*16 + l15;
    float ba_ = bias[e*H2X + j];
    float bg_ = bias[e*H2X + INNER + j];
    #pragma unroll
    for(int mi=0;mi<4;mi++){
      int rl = wm*64 + mi*16 + quad*4;
      #pragma unroll
      for(int r=0;r<4;r++){
        int row = mtile*128 + rl + r;
        if(row < cn){
          float a = aca[mi][ni][r]*inv_scale + ba_;
          float g = acg[mi][ni][r]*inv_scale + bg_;
          out[(size_t)(base+row)*INNER + j] = f2fp8(a*g*fsigmoid(g)*out_scale);
        }
      }
    }
  }
}

__global__ __launch_bounds__(256) void gemm_sg1_kernel(
    const uint8_t* __restrict__ A, const uint8_t* __restrict__ wt,
    const float* __restrict__ bias, const int* __restrict__ cnt, uint8_t* __restrict__ out){
  gemm_swiglu_impl<DIM>(A, wt, bias, cnt, out, 1.f/64.f, 64.f);
}
__global__ __launch_bounds__(256) void gemm_sg2_kernel(
    const uint8_t* __restrict__ A, const uint8_t* __restrict__ wt,
    const float* __restrict__ bias, const int* __restrict__ cnt, uint8_t* __restrict__ out){
  gemm_swiglu_impl<INNER>(A, wt, bias, cnt, out, 1.f/512.f, 2097152.f);
}

// ---------------- fp8 expert output GEMM, split-K=2 -> two eo slabs ----------------
__global__ __launch_bounds__(256) void gemm_out_kernel(
    const uint8_t* __restrict__ h2, const uint8_t* __restrict__ w3t,
    const float* __restrict__ be3, const int* __restrict__ cnt, float* __restrict__ eo){
  int e = blockIdx.z;
  int cn = cnt[e];
  int mtile = blockIdx.y;
  if (mtile*128 >= cn) return;
  int base = prefix_cnt(cnt, e);
  int jt = blockIdx.x % 3, kh = blockIdx.x / 3;
  int n0 = jt*128;
  int koff = kh*768;
  float* eos = eo + (size_t)kh*NASSIGN*DIM;
  int tid=threadIdx.x, lane=tid&63, wid=tid>>6, wm=wid&1, wn=wid>>1;
  int l15=lane&15, quad=lane>>4;
  __shared__ alignas(16) uint8_t sA[128*64];
  __shared__ alignas(16) uint8_t sB[128*64];
  int rA = tid>>2;
  int scc = ((tid&3)*16) ^ (((tid>>2)&3)*16);
  int lr0 = mtile*128 + rA, lr1 = lr0+64;
  const uint8_t* a0p = h2 + (size_t)(base + min(lr0, cn-1))*INNER + koff;
  const uint8_t* a1p = h2 + (size_t)(base + min(lr1, cn-1))*INNER + koff;
  const uint8_t* b0p = w3t + ((size_t)e*DIM + n0 + rA)*INNER + koff;
  const uint8_t* b1p = w3t + ((size_t)e*DIM + n0 + 64 + rA)*INNER + koff;
  floatx4 acc[4][4];
  #pragma unroll
  for(int i=0;i<4;i++)
    #pragma unroll
    for(int j=0;j<4;j++) acc[i][j]=(floatx4){0.f,0.f,0.f,0.f};
  int swz = (l15&3)*16;
  for(int kt=0; kt<768; kt+=64){
    __syncthreads();
    gload16(a0p + kt + scc, &sA[wid*1024]);
    gload16(a1p + kt + scc, &sA[4096 + wid*1024]);
    gload16(b0p + kt + scc, &sB[wid*1024]);
    gload16(b1p + kt + scc, &sB[4096 + wid*1024]);
    __syncthreads();
    #pragma unroll
    for(int s=0;s<2;s++){
      int kb = (s*32 + quad*8) ^ swz;
      long af[4], bfr[4];
      #pragma unroll
      for(int mi=0;mi<4;mi++) af[mi] = *(const long*)&sA[(wm*64+mi*16+l15)*64 + kb];
      #pragma unroll
      for(int ni=0;ni<4;ni++) bfr[ni] = *(const long*)&sB[(wn*64+ni*16+l15)*64 + kb];
      #pragma unroll
      for(int mi=0;mi<4;mi++)
        #pragma unroll
        for(int ni=0;ni<4;ni++)
          acc[mi][ni] = __builtin_amdgcn_mfma_f32_16x16x32_fp8_fp8(af[mi], bfr[ni], acc[mi][ni],0,0,0);
    }
  }
  const float OSC = 5.9604644775390625e-8f;  // 2^-24
  #pragma unroll
  for(int ni=0;ni<4;ni++){
    int col = n0 + wn*64 + ni*16 + l15;
    float b3 = (kh==0) ? be3[e*DIM + col] : 0.f;
    #pragma unroll
    for(int mi=0;mi<4;mi++){
      int rl = wm*64 + mi*16 + quad*4;
      #pragma unroll
      for(int r=0;r<4;r++){
        int row = mtile*128 + rl + r;
        if(row < cn){
          eos[(size_t)(base+row)*DIM + col] = acc[mi][ni][r]*OSC + b3;
        }
      }
    }
  }
}

// ---------------- combine expert outputs + pooled accumulation ----------------
__global__ __launch_bounds__(384) void combine_pooled_kernel(const float* __restrict__ eo,
    const int* __restrict__ inv, const float* __restrict__ rwt,
    const float* __restrict__ x, const float* __restrict__ sres,
    float* __restrict__ y, float* __restrict__ pooled){
  int b = blockIdx.y, t0 = blockIdx.x*8;
  int d = threadIdx.x;
  const float* eo1 = eo + (size_t)NASSIGN*DIM;
  float sr = sres[d];
  float acc = 0.f;
  for(int t=0;t<8;t++){
    int n = b*NT + t0 + t;
    int p0 = inv[2*n], p1 = inv[2*n+1];
    float w0 = rwt[2*n], w1 = rwt[2*n+1];
    size_t o = (size_t)n*DIM + d;
    float yv = y[o] + w0*(eo[(size_t)p0*DIM+d] + eo1[(size_t)p0*DIM+d])
                    + w1*(eo[(size_t)p1*DIM+d] + eo1[(size_t)p1*DIM+d]);
    y[o] = yv;
    acc += x[o]*sr + yv;
  }
  atomicAdd(&pooled[b*DIM+d], acc*(1.f/NT));
}

// ---------------- fused gate + final ----------------
__global__ __launch_bounds__(384) void gatefinal_kernel(const float* __restrict__ pooled,
    const float* __restrict__ sw1, const float* __restrict__ sb1,
    const float* __restrict__ sw2, const float* __restrict__ sb2,
    const float* __restrict__ res, const float* __restrict__ y, float* __restrict__ out){
  int b = blockIdx.y, t0 = blockIdx.x*8;
  int d = threadIdx.x;
  __shared__ float sp[DIM];
  __shared__ float sh[SQZ];
  sp[d] = pooled[b*DIM+d];
  __syncthreads();
  if(d<SQZ){
    float a = sb1[d];
    for(int k=0;k<DIM;k++) a += sp[k]*sw1[k*SQZ+d];
    sh[d] = a*fsigmoid(a);
  }
  __syncthreads();
  float a = sb2[d];
  #pragma unroll
  for(int j=0;j<SQZ;j++) a += sh[j]*sw2[j*DIM+d];
  float g = fsigmoid(a);
  for(int t=0;t<8;t++){
    size_t o = ((size_t)b*NT + t0 + t)*DIM + d;
    out[o] = res[o] + y[o]*g;
  }
}

extern "C" void kernel_launch(void* const* d_in, const int* in_sizes, int n_in,
                              void* d_out, int out_size, void* d_ws, size_t ws_size,
                              hipStream_t stream) {
  (void)in_sizes; (void)n_in; (void)out_size; (void)ws_size;
  const float* res   = (const float*)d_in[0];
  const float* ln_g  = (const float*)d_in[1];
  const float* ln_b  = (const float*)d_in[2];
  const float* conv_w= (const float*)d_in[3];
  const float* conv_b= (const float*)d_in[4];
  const float* rw1   = (const float*)d_in[5];
  const float* rb1   = (const float*)d_in[6];
  const float* rw2   = (const float*)d_in[7];
  const float* rb2   = (const float*)d_in[8];
  const float* we1   = (const float*)d_in[9];
  const float* be1   = (const float*)d_in[10];
  const float* we2   = (const float*)d_in[11];
  const float* be2   = (const float*)d_in[12];
  const float* we3   = (const float*)d_in[13];
  const float* be3   = (const float*)d_in[14];
  const float* sw1   = (const float*)d_in[15];
  const float* sb1   = (const float*)d_in[16];
  const float* sw2   = (const float*)d_in[17];
  const float* sb2   = (const float*)d_in[18];
  const float* sres  = (const float*)d_in[19];
  float* out = (float*)d_out;

  char* ws = (char*)d_ws;
  size_t off = 0;
  auto alloc = [&](size_t bytes)->void*{ void* p = ws + off; off = (off + bytes + 255) & ~(size_t)255; return p; };
  float*          x     = (float*)alloc((size_t)NN*DIM*4);
  float*          y     = (float*)alloc((size_t)NN*DIM*4);
  float*          eo    = (float*)alloc((size_t)2*NASSIGN*DIM*4);
  unsigned short* tokb  = (unsigned short*)alloc((size_t)NN*DIM*2);
  uint8_t*        tokc  = (uint8_t*)alloc((size_t)NASSIGN*DIM);
  unsigned short* g1    = (unsigned short*)alloc((size_t)NN*DIM*2);
  uint8_t*        w1t   = (uint8_t*)alloc((size_t)NE*H2X*DIM);
  uint8_t*        w2t   = (uint8_t*)alloc((size_t)NE*H2X*INNER);
  uint8_t*        w3t   = (uint8_t*)alloc((size_t)NE*DIM*INNER);
  unsigned short* rw1t  = (unsigned short*)alloc((size_t)DIM*DIM*2);
  uint8_t*        h1    = (uint8_t*)alloc((size_t)NASSIGN*INNER);
  uint8_t*        h2b   = (uint8_t*)alloc((size_t)NASSIGN*INNER);
  int*            ridx  = (int*)alloc((size_t)NASSIGN*4);
  float*          rwt   = (float*)alloc((size_t)NASSIGN*4);
  int*            inv   = (int*)alloc((size_t)NASSIGN*4);
  int*            cnt   = (int*)alloc(128);
  int*            cnt2  = cnt + 8;
  float*          pooled= (float*)alloc((size_t)NB*DIM*4);

  tr_all_kernel<<<TR_N1+TR_N2+TR_N3+TR_N4, dim3(32,8), 0, stream>>>(
      we1, w1t, we2, w2t, we3, w3t, rw1, rw1t);
  convln_kernel<<<dim3(NT/CTT, NB), 384, 0, stream>>>(
      res, ln_g, ln_b, conv_w, conv_b, x, tokb, y);
  router_g1_kernel<<<dim3(DIM/128, NN/128), 256, 0, stream>>>(tokb, rw1t, rb1, g1, cnt);
  router2_kernel<<<NN/4, 256, 0, stream>>>(g1, rw2, rb2, ridx, rwt, cnt);
  fillcompact_kernel<<<NASSIGN/256, 256, 0, stream>>>(ridx, cnt, cnt2, inv, tokb, tokc, pooled);

  gemm_sg1_kernel<<<dim3(INNER/64, NN/128, NE), 256, 0, stream>>>(tokc, w1t, be1, cnt, h1);
  gemm_sg2_kernel<<<dim3(INNER/64, NN/128, NE), 256, 0, stream>>>(h1, w2t, be2, cnt, h2b);
  gemm_out_kernel<<<dim3(6, NN/128, NE), 256, 0, stream>>>(h2b, w3t, be3, cnt, eo);
  combine_pooled_kernel<<<dim3(NT/8, NB), 384, 0, stream>>>(
      eo, inv, rwt, x, sres, y, pooled);
  gatefinal_kernel<<<dim3(NT/8, NB), 384, 0, stream>>>(
      pooled, sw1, sb1, sw2, sb2, res, y, out);
}

// Round 6
// 594.052 us; speedup vs baseline: 1.1723x; 1.0010x over previous
//
#include <hip/hip_runtime.h>
#include <stdint.h>

#define DIM 384
#define INNER 1536
#define H2X 3072
#define NE 5
#define NB 4
#define NT 1024
#define NN (NB*NT)
#define KSZ 31
#define SQZ 48
#define NASSIGN (NN*2)

typedef float floatx4 __attribute__((ext_vector_type(4)));
typedef __bf16 bf16x8 __attribute__((ext_vector_type(8)));

__device__ __forceinline__ unsigned short f2bs(float f){
  union { float f; uint32_t u; } v; v.f = f;
  uint32_t r = (v.u + 0x7fffu + ((v.u >> 16) & 1u)) >> 16;
  return (unsigned short)r;
}
__device__ __forceinline__ float bs2f(unsigned short s){
  union { uint32_t u; float f; } v; v.u = ((uint32_t)s) << 16; return v.f;
}
__device__ __forceinline__ float fsigmoid(float x){ return 1.f/(1.f+__expf(-x)); }

__device__ __forceinline__ uint32_t pk2_lo(float a, float b, uint32_t old){
  return __builtin_amdgcn_cvt_pk_fp8_f32(a, b, old, false);
}
__device__ __forceinline__ uint32_t pk2_hi(float a, float b, uint32_t old){
  return __builtin_amdgcn_cvt_pk_fp8_f32(a, b, old, true);
}
__device__ __forceinline__ uint8_t f2fp8(float a){
  return (uint8_t)__builtin_amdgcn_cvt_pk_fp8_f32(a, 0.f, 0u, false);
}

__device__ __forceinline__ void gload16(const void* g, void* l){
  __builtin_amdgcn_global_load_lds(
    reinterpret_cast<const __attribute__((address_space(1))) unsigned int*>(
        reinterpret_cast<uintptr_t>(g)),
    reinterpret_cast<__attribute__((address_space(3))) unsigned int*>(
        (unsigned int)reinterpret_cast<uintptr_t>(l)),
    16, 0, 0);
}

__device__ __forceinline__ int prefix_cnt(const int* __restrict__ cnt, int e){
  int base = 0;
  #pragma unroll
  for(int k=0;k<NE;k++) base += (k<e) ? cnt[k] : 0;
  return base;
}

#define WSCALE 8.f

// ---------------- weight transposes (one dispatch) ----------------
__device__ __forceinline__ void do_tr_bf16(const float* __restrict__ in,
    unsigned short* __restrict__ out, int R, int C, int cx, int cy){
  __shared__ float tile[32][65];
  int c0 = cx*32, r0 = cy*64;
  int tx = threadIdx.x, ty = threadIdx.y;
  #pragma unroll
  for (int i=0;i<8;i++){
    int r = ty + i*8;
    tile[tx][r] = in[(size_t)(r0+r)*C + c0 + tx];
  }
  __syncthreads();
  #pragma unroll
  for (int i=0;i<4;i++){
    int c = ty + i*8;
    uint32_t lo = f2bs(tile[c][2*tx]);
    uint32_t hi = f2bs(tile[c][2*tx+1]);
    *(uint32_t*)&out[(size_t)(c0+c)*R + r0 + 2*tx] = lo | (hi<<16);
  }
}
__device__ __forceinline__ void do_tr_fp8(const float* __restrict__ in,
    uint8_t* __restrict__ out, int R, int C, int cx, int cy){
  __shared__ float tile[32][65];
  int c0 = cx*32, r0 = cy*64;
  int tx = threadIdx.x, ty = threadIdx.y;
  #pragma unroll
  for (int i=0;i<8;i++){
    int r = ty + i*8;
    tile[tx][r] = in[(size_t)(r0+r)*C + c0 + tx];
  }
  __syncthreads();
  #pragma unroll
  for (int i=0;i<4;i++){
    int c = ty + i*8;
    uint32_t v = pk2_lo(tile[c][2*tx]*WSCALE, tile[c][2*tx+1]*WSCALE, 0u);
    *(unsigned short*)&out[(size_t)(c0+c)*R + r0 + 2*tx] = (unsigned short)(v & 0xffffu);
  }
}

#define TR_N1 (96*6*5)
#define TR_N2 (96*24*5)
#define TR_N3 (12*24*5)
#define TR_N4 (12*6)
__global__ __launch_bounds__(256) void tr_all_kernel(
    const float* __restrict__ we1, uint8_t* __restrict__ w1t,
    const float* __restrict__ we2, uint8_t* __restrict__ w2t,
    const float* __restrict__ we3, uint8_t* __restrict__ w3t,
    const float* __restrict__ rw1, unsigned short* __restrict__ rw1t){
  int bid = blockIdx.x;
  if (bid < TR_N1){
    int z = bid/(96*6), rem = bid%(96*6);
    do_tr_fp8(we1 + (size_t)z*384*3072, w1t + (size_t)z*384*3072, 384, 3072, rem%96, rem/96);
  } else if (bid < TR_N1+TR_N2){
    int idx = bid - TR_N1;
    int z = idx/(96*24), rem = idx%(96*24);
    do_tr_fp8(we2 + (size_t)z*1536*3072, w2t + (size_t)z*1536*3072, 1536, 3072, rem%96, rem/96);
  } else if (bid < TR_N1+TR_N2+TR_N3){
    int idx = bid - TR_N1 - TR_N2;
    int z = idx/(12*24), rem = idx%(12*24);
    do_tr_fp8(we3 + (size_t)z*1536*384, w3t + (size_t)z*1536*384, 1536, 384, rem%12, rem/12);
  } else {
    int idx = bid - TR_N1 - TR_N2 - TR_N3;
    do_tr_bf16(rw1, rw1t, 384, 384, idx%12, idx/12);
  }
}

// ---------------- fused LayerNorm + depthwise conv ----------------
#define CTT 16
__global__ __launch_bounds__(384) void convln_kernel(const float* __restrict__ res,
    const float* __restrict__ ln_g, const float* __restrict__ ln_b,
    const float* __restrict__ cw, const float* __restrict__ cb,
    float* __restrict__ x, unsigned short* __restrict__ tokb, float* __restrict__ y){
  __shared__ float tile[(CTT+30)*DIM];
  int b = blockIdx.y, t0 = blockIdx.x*CTT;
  int tid = threadIdx.x;
  int w = tid>>6, lane = tid&63;
  float gw[6], bw[6];
  #pragma unroll
  for(int i=0;i<6;i++){ gw[i]=ln_g[i*64+lane]; bw[i]=ln_b[i*64+lane]; }
  for(int r=w; r<CTT+30; r+=6){
    int gt = t0 - 15 + r;
    if(gt>=0 && gt<NT){
      const float* rp = res + ((size_t)b*NT+gt)*DIM;
      float v[6]; float s=0.f;
      #pragma unroll
      for(int i=0;i<6;i++){ v[i]=rp[i*64+lane]; s+=v[i]; }
      #pragma unroll
      for(int o=32;o;o>>=1) s += __shfl_down(s,o);
      s = __shfl(s,0);
      float mean = s*(1.f/DIM);
      float q=0.f;
      #pragma unroll
      for(int i=0;i<6;i++){ v[i]-=mean; q+=v[i]*v[i]; }
      #pragma unroll
      for(int o=32;o;o>>=1) q += __shfl_down(q,o);
      q = __shfl(q,0);
      float rstd = rsqrtf(q*(1.f/DIM) + 1e-5f);
      #pragma unroll
      for(int i=0;i<6;i++) tile[r*DIM+i*64+lane] = v[i]*rstd*gw[i]+bw[i];
    } else {
      #pragma unroll
      for(int i=0;i<6;i++) tile[r*DIM+i*64+lane] = 0.f;
    }
  }
  __syncthreads();
  float cwr[KSZ];
  #pragma unroll
  for(int k=0;k<KSZ;k++) cwr[k] = cw[tid*KSZ+k];
  float bias = cb[tid];
  for(int t=0;t<CTT;t++){
    float acc = bias;
    #pragma unroll
    for(int k=0;k<KSZ;k++) acc += tile[(t+k)*DIM+tid]*cwr[k];
    size_t o = ((size_t)b*NT + t0 + t)*DIM + tid;
    y[o]=acc; tokb[o]=f2bs(acc);
    x[o]=tile[(t+15)*DIM+tid];
  }
}

// ---------------- router GEMM1 (bf16; also zeroes cnt/cnt2) ----------------
__global__ __launch_bounds__(256) void router_g1_kernel(const unsigned short* __restrict__ tokb,
    const unsigned short* __restrict__ rw1t, const float* __restrict__ rb1,
    unsigned short* __restrict__ g1, int* __restrict__ cnt){
  int tid = threadIdx.x;
  if(blockIdx.x==0 && blockIdx.y==0 && tid<32) cnt[tid]=0;
  __shared__ alignas(16) unsigned short sA[128*32];
  __shared__ alignas(16) unsigned short sB[128*32];
  int n0 = blockIdx.x*128, m0 = blockIdx.y*128;
  int lane = tid&63, wid = tid>>6, wm = wid&1, wn = wid>>1;
  int l15 = lane&15, quad = lane>>4;
  floatx4 acc[4][4];
  #pragma unroll
  for(int i=0;i<4;i++)
    #pragma unroll
    for(int j=0;j<4;j++) acc[i][j]=(floatx4){0.f,0.f,0.f,0.f};
  int rA = tid>>2, c8 = tid&3;
  const unsigned short* a0p = tokb + (size_t)(m0+rA)*DIM;
  const unsigned short* a1p = tokb + (size_t)(m0+64+rA)*DIM;
  const unsigned short* b0p = rw1t + (size_t)(n0+rA)*DIM;
  const unsigned short* b1p = rw1t + (size_t)(n0+64+rA)*DIM;
  for(int kt=0; kt<DIM; kt+=32){
    __syncthreads();
    gload16(a0p + kt + c8*8, &sA[wid*512]);
    gload16(a1p + kt + c8*8, &sA[2048 + wid*512]);
    gload16(b0p + kt + c8*8, &sB[wid*512]);
    gload16(b1p + kt + c8*8, &sB[2048 + wid*512]);
    __syncthreads();
    bf16x8 af[4], bfr[4];
    #pragma unroll
    for(int mi=0;mi<4;mi++) af[mi] = *(const bf16x8*)&sA[(wm*64+mi*16+l15)*32 + quad*8];
    #pragma unroll
    for(int ni=0;ni<4;ni++) bfr[ni] = *(const bf16x8*)&sB[(wn*64+ni*16+l15)*32 + quad*8];
    #pragma unroll
    for(int mi=0;mi<4;mi++)
      #pragma unroll
      for(int ni=0;ni<4;ni++)
        acc[mi][ni] = __builtin_amdgcn_mfma_f32_16x16x32_bf16(af[mi], bfr[ni], acc[mi][ni],0,0,0);
  }
  #pragma unroll
  for(int ni=0;ni<4;ni++){
    int col = n0 + wn*64 + ni*16 + l15;
    float bias = rb1[col];
    #pragma unroll
    for(int mi=0;mi<4;mi++){
      int rowb = m0 + wm*64 + mi*16 + quad*4;
      #pragma unroll
      for(int r=0;r<4;r++){
        float v = acc[mi][ni][r] + bias;
        g1[(size_t)(rowb+r)*DIM + col] = f2bs(v*fsigmoid(v));
      }
    }
  }
}

// ---------------- router2 ----------------
__global__ __launch_bounds__(256) void router2_kernel(const unsigned short* __restrict__ g1,
    const float* __restrict__ rw2, const float* __restrict__ rb2,
    int* __restrict__ ridx, float* __restrict__ rwt, int* __restrict__ cnt){
  int wid = threadIdx.x>>6, lane = threadIdx.x&63;
  int n = blockIdx.x*4 + wid;
  float s[NE]={0.f,0.f,0.f,0.f,0.f};
  #pragma unroll
  for(int i=0;i<6;i++){
    int d = lane + i*64;
    float gv = bs2f(g1[(size_t)n*DIM+d]);
    #pragma unroll
    for(int e=0;e<NE;e++) s[e] += gv * rw2[d*NE+e];
  }
  #pragma unroll
  for(int e=0;e<NE;e++)
    #pragma unroll
    for(int o=32;o;o>>=1) s[e] += __shfl_down(s[e],o);
  if(lane==0){
    float r[NE];
    #pragma unroll
    for(int e=0;e<NE;e++) r[e]=s[e]+rb2[e];
    int e0=0;
    for(int e=1;e<NE;e++) if(r[e]>r[e0]) e0=e;
    int e1=-1;
    for(int e=0;e<NE;e++){ if(e==e0) continue; if(e1<0||r[e]>r[e1]) e1=e; }
    float w0 = 1.f/(1.f+__expf(r[e1]-r[e0]));
    ridx[2*n]=e0; ridx[2*n+1]=e1;
    rwt[2*n]=w0; rwt[2*n+1]=1.f-w0;
    atomicAdd(&cnt[e0],1); atomicAdd(&cnt[e1],1);
  }
}

// ---------------- fill positions + compact tokens to fp8 (x8) + zero pooled ----------------
__global__ __launch_bounds__(256) void fillcompact_kernel(const int* __restrict__ ridx,
    const int* __restrict__ cnt, int* __restrict__ cnt2,
    int* __restrict__ inv, const unsigned short* __restrict__ tokb,
    uint8_t* __restrict__ tokc, float* __restrict__ pooled){
  __shared__ int sSrc[256], sPos[256];
  int tid = threadIdx.x;
  if(blockIdx.x==0){
    for(int i=tid;i<NB*DIM;i+=256) pooled[i]=0.f;
  }
  int i = blockIdx.x*256 + tid;
  int e = ridx[i];
  int base = prefix_cnt(cnt, e);
  int pos = base + atomicAdd(&cnt2[e],1);
  inv[i] = pos;
  sSrc[tid] = i>>1;
  sPos[tid] = pos;
  __syncthreads();
  int w = tid>>6, lane = tid&63;
  for(int j=0;j<64;j++){
    int idx = w*64+j;
    int src = sSrc[idx], dst = sPos[idx];
    if(lane<48){
      uint4 sv = ((const uint4*)&tokb[(size_t)src*DIM])[lane];
      float f0=bs2f(sv.x&0xffff)*WSCALE, f1=bs2f(sv.x>>16)*WSCALE;
      float f2=bs2f(sv.y&0xffff)*WSCALE, f3=bs2f(sv.y>>16)*WSCALE;
      float f4=bs2f(sv.z&0xffff)*WSCALE, f5=bs2f(sv.z>>16)*WSCALE;
      float f6=bs2f(sv.w&0xffff)*WSCALE, f7=bs2f(sv.w>>16)*WSCALE;
      uint32_t lo = pk2_hi(f2,f3, pk2_lo(f0,f1,0u));
      uint32_t hi = pk2_hi(f6,f7, pk2_lo(f4,f5,0u));
      uint2 pv; pv.x = lo; pv.y = hi;
      ((uint2*)&tokc[(size_t)dst*DIM])[lane] = pv;
    }
  }
}

// ---------------- fp8 expert GEMM + fused SwiGLU ----------------
// 128-row x (128 value + 128 gate) tile; 4 waves in 2x2; 4x4 x2 acc per wave.
// LDS granule swizzle: global chunk cg = cl ^ ((row>>1)&3); reader granule
// p = (s*4+quad) ^ (l15&6)  -> 2-way max bank aliasing on ds_read_b64.
template<int KDIM>
__device__ __forceinline__ void gemm_swiglu_impl(
    const uint8_t* __restrict__ A,
    const uint8_t* __restrict__ wt, const float* __restrict__ bias,
    const int* __restrict__ cnt, uint8_t* __restrict__ out,
    float inv_scale, float out_scale){
  int e = blockIdx.z;
  int cn = cnt[e];
  int mtile = blockIdx.y;
  if (mtile*128 >= cn) return;
  int base = prefix_cnt(cnt, e);
  int j0 = blockIdx.x*128;
  int tid=threadIdx.x, lane=tid&63, wid=tid>>6, wm=wid&1, wn=wid>>1;
  int l15=lane&15, quad=lane>>4;
  __shared__ alignas(16) uint8_t sA[128*64];
  __shared__ alignas(16) uint8_t sBa[128*64];
  __shared__ alignas(16) uint8_t sBg[128*64];
  int rA = tid>>2;
  int gb = ((tid&3) ^ ((tid>>3)&3))*16;   // swizzled global chunk offset
  const uint8_t* a0p = A + (size_t)(base + min(mtile*128+rA, cn-1))*KDIM + gb;
  const uint8_t* a1p = A + (size_t)(base + min(mtile*128+64+rA, cn-1))*KDIM + gb;
  const uint8_t* b0p = wt + ((size_t)e*H2X + j0 + rA)*KDIM + gb;
  const uint8_t* b1p = wt + ((size_t)e*H2X + j0 + 64 + rA)*KDIM + gb;
  const uint8_t* g0p = wt + ((size_t)e*H2X + INNER + j0 + rA)*KDIM + gb;
  const uint8_t* g1p = wt + ((size_t)e*H2X + INNER + j0 + 64 + rA)*KDIM + gb;
  floatx4 aca[4][4], acg[4][4];
  #pragma unroll
  for(int i=0;i<4;i++)
    #pragma unroll
    for(int j=0;j<4;j++){ aca[i][j]=(floatx4){0.f,0.f,0.f,0.f}; acg[i][j]=(floatx4){0.f,0.f,0.f,0.f}; }
  int ldsw = wid*1024;
  for(int kt=0; kt<KDIM; kt+=64){
    __syncthreads();
    gload16(a0p + kt, &sA[ldsw]);
    gload16(a1p + kt, &sA[4096+ldsw]);
    gload16(b0p + kt, &sBa[ldsw]);
    gload16(b1p + kt, &sBa[4096+ldsw]);
    gload16(g0p + kt, &sBg[ldsw]);
    gload16(g1p + kt, &sBg[4096+ldsw]);
    __syncthreads();
    #pragma unroll
    for(int s=0;s<2;s++){
      int pq = (((s*4+quad) ^ (l15&6)))*8;
      long af[4], ba[4], bg[4];
      #pragma unroll
      for(int mi=0;mi<4;mi++) af[mi] = *(const long*)&sA[(wm*64+mi*16+l15)*64 + pq];
      #pragma unroll
      for(int ni=0;ni<4;ni++){
        ba[ni] = *(const long*)&sBa[(wn*64+ni*16+l15)*64 + pq];
        bg[ni] = *(const long*)&sBg[(wn*64+ni*16+l15)*64 + pq];
      }
      #pragma unroll
      for(int mi=0;mi<4;mi++)
        #pragma unroll
        for(int ni=0;ni<4;ni++){
          aca[mi][ni] = __builtin_amdgcn_mfma_f32_16x16x32_fp8_fp8(af[mi], ba[ni], aca[mi][ni],0,0,0);
          acg[mi][ni] = __builtin_amdgcn_mfma_f32_16x16x32_fp8_fp8(af[mi], bg[ni], acg[mi][ni],0,0,0);
        }
    }
  }
  #pragma unroll
  for(int ni=0;ni<4;ni++){
    int j = j0 + wn*64 + ni*16 + l15;
    float ba_ = bias[e*H2X + j];
    float bg_ = bias[e*H2X + INNER + j];
    #pragma unroll
    for(int mi=0;mi<4;mi++){
      int rl = wm*64 + mi*16 + quad*4;
      #pragma unroll
      for(int r=0;r<4;r++){
        int row = mtile*128 + rl + r;
        if(row < cn){
          float a = aca[mi][ni][r]*inv_scale + ba_;
          float g = acg[mi][ni][r]*inv_scale + bg_;
          out[(size_t)(base+row)*INNER + j] = f2fp8(a*g*fsigmoid(g)*out_scale);
        }
      }
    }
  }
}

__global__ __launch_bounds__(256,2) void gemm_sg1_kernel(
    const uint8_t* __restrict__ A, const uint8_t* __restrict__ wt,
    const float* __restrict__ bias, const int* __restrict__ cnt, uint8_t* __restrict__ out){
  gemm_swiglu_impl<DIM>(A, wt, bias, cnt, out, 1.f/64.f, 64.f);
}
__global__ __launch_bounds__(256,2) void gemm_sg2_kernel(
    const uint8_t* __restrict__ A, const uint8_t* __restrict__ wt,
    const float* __restrict__ bias, const int* __restrict__ cnt, uint8_t* __restrict__ out){
  gemm_swiglu_impl<INNER>(A, wt, bias, cnt, out, 1.f/512.f, 2097152.f);
}

// ---------------- fp8 expert output GEMM, split-K=2 -> two eo slabs ----------------
__global__ __launch_bounds__(256) void gemm_out_kernel(
    const uint8_t* __restrict__ h2, const uint8_t* __restrict__ w3t,
    const float* __restrict__ be3, const int* __restrict__ cnt, float* __restrict__ eo){
  int e = blockIdx.z;
  int cn = cnt[e];
  int mtile = blockIdx.y;
  if (mtile*128 >= cn) return;
  int base = prefix_cnt(cnt, e);
  int jt = blockIdx.x % 3, kh = blockIdx.x / 3;
  int n0 = jt*128;
  int koff = kh*768;
  float* eos = eo + (size_t)kh*NASSIGN*DIM;
  int tid=threadIdx.x, lane=tid&63, wid=tid>>6, wm=wid&1, wn=wid>>1;
  int l15=lane&15, quad=lane>>4;
  __shared__ alignas(16) uint8_t sA[128*64];
  __shared__ alignas(16) uint8_t sB[128*64];
  int rA = tid>>2;
  int gb = ((tid&3) ^ ((tid>>3)&3))*16;
  const uint8_t* a0p = h2 + (size_t)(base + min(mtile*128+rA, cn-1))*INNER + koff + gb;
  const uint8_t* a1p = h2 + (size_t)(base + min(mtile*128+64+rA, cn-1))*INNER + koff + gb;
  const uint8_t* b0p = w3t + ((size_t)e*DIM + n0 + rA)*INNER + koff + gb;
  const uint8_t* b1p = w3t + ((size_t)e*DIM + n0 + 64 + rA)*INNER + koff + gb;
  floatx4 acc[4][4];
  #pragma unroll
  for(int i=0;i<4;i++)
    #pragma unroll
    for(int j=0;j<4;j++) acc[i][j]=(floatx4){0.f,0.f,0.f,0.f};
  int ldsw = wid*1024;
  for(int kt=0; kt<768; kt+=64){
    __syncthreads();
    gload16(a0p + kt, &sA[ldsw]);
    gload16(a1p + kt, &sA[4096+ldsw]);
    gload16(b0p + kt, &sB[ldsw]);
    gload16(b1p + kt, &sB[4096+ldsw]);
    __syncthreads();
    #pragma unroll
    for(int s=0;s<2;s++){
      int pq = (((s*4+quad) ^ (l15&6)))*8;
      long af[4], bfr[4];
      #pragma unroll
      for(int mi=0;mi<4;mi++) af[mi] = *(const long*)&sA[(wm*64+mi*16+l15)*64 + pq];
      #pragma unroll
      for(int ni=0;ni<4;ni++) bfr[ni] = *(const long*)&sB[(wn*64+ni*16+l15)*64 + pq];
      #pragma unroll
      for(int mi=0;mi<4;mi++)
        #pragma unroll
        for(int ni=0;ni<4;ni++)
          acc[mi][ni] = __builtin_amdgcn_mfma_f32_16x16x32_fp8_fp8(af[mi], bfr[ni], acc[mi][ni],0,0,0);
    }
  }
  const float OSC = 5.9604644775390625e-8f;  // 2^-24
  #pragma unroll
  for(int ni=0;ni<4;ni++){
    int col = n0 + wn*64 + ni*16 + l15;
    float b3 = (kh==0) ? be3[e*DIM + col] : 0.f;
    #pragma unroll
    for(int mi=0;mi<4;mi++){
      int rl = wm*64 + mi*16 + quad*4;
      #pragma unroll
      for(int r=0;r<4;r++){
        int row = mtile*128 + rl + r;
        if(row < cn){
          eos[(size_t)(base+row)*DIM + col] = acc[mi][ni][r]*OSC + b3;
        }
      }
    }
  }
}

// ---------------- combine expert outputs + pooled accumulation ----------------
__global__ __launch_bounds__(384) void combine_pooled_kernel(const float* __restrict__ eo,
    const int* __restrict__ inv, const float* __restrict__ rwt,
    const float* __restrict__ x, const float* __restrict__ sres,
    float* __restrict__ y, float* __restrict__ pooled){
  int b = blockIdx.y, t0 = blockIdx.x*8;
  int d = threadIdx.x;
  const float* eo1 = eo + (size_t)NASSIGN*DIM;
  float sr = sres[d];
  float acc = 0.f;
  for(int t=0;t<8;t++){
    int n = b*NT + t0 + t;
    int p0 = inv[2*n], p1 = inv[2*n+1];
    float w0 = rwt[2*n], w1 = rwt[2*n+1];
    size_t o = (size_t)n*DIM + d;
    float yv = y[o] + w0*(eo[(size_t)p0*DIM+d] + eo1[(size_t)p0*DIM+d])
                    + w1*(eo[(size_t)p1*DIM+d] + eo1[(size_t)p1*DIM+d]);
    y[o] = yv;
    acc += x[o]*sr + yv;
  }
  atomicAdd(&pooled[b*DIM+d], acc*(1.f/NT));
}

// ---------------- fused gate + final ----------------
__global__ __launch_bounds__(384) void gatefinal_kernel(const float* __restrict__ pooled,
    const float* __restrict__ sw1, const float* __restrict__ sb1,
    const float* __restrict__ sw2, const float* __restrict__ sb2,
    const float* __restrict__ res, const float* __restrict__ y, float* __restrict__ out){
  int b = blockIdx.y, t0 = blockIdx.x*8;
  int d = threadIdx.x;
  __shared__ float sp[DIM];
  __shared__ float sh[SQZ];
  sp[d] = pooled[b*DIM+d];
  __syncthreads();
  if(d<SQZ){
    float a = sb1[d];
    for(int k=0;k<DIM;k++) a += sp[k]*sw1[k*SQZ+d];
    sh[d] = a*fsigmoid(a);
  }
  __syncthreads();
  float a = sb2[d];
  #pragma unroll
  for(int j=0;j<SQZ;j++) a += sh[j]*sw2[j*DIM+d];
  float g = fsigmoid(a);
  for(int t=0;t<8;t++){
    size_t o = ((size_t)b*NT + t0 + t)*DIM + d;
    out[o] = res[o] + y[o]*g;
  }
}

extern "C" void kernel_launch(void* const* d_in, const int* in_sizes, int n_in,
                              void* d_out, int out_size, void* d_ws, size_t ws_size,
                              hipStream_t stream) {
  (void)in_sizes; (void)n_in; (void)out_size; (void)ws_size;
  const float* res   = (const float*)d_in[0];
  const float* ln_g  = (const float*)d_in[1];
  const float* ln_b  = (const float*)d_in[2];
  const float* conv_w= (const float*)d_in[3];
  const float* conv_b= (const float*)d_in[4];
  const float* rw1   = (const float*)d_in[5];
  const float* rb1   = (const float*)d_in[6];
  const float* rw2   = (const float*)d_in[7];
  const float* rb2   = (const float*)d_in[8];
  const float* we1   = (const float*)d_in[9];
  const float* be1   = (const float*)d_in[10];
  const float* we2   = (const float*)d_in[11];
  const float* be2   = (const float*)d_in[12];
  const float* we3   = (const float*)d_in[13];
  const float* be3   = (const float*)d_in[14];
  const float* sw1   = (const float*)d_in[15];
  const float* sb1   = (const float*)d_in[16];
  const float* sw2   = (const float*)d_in[17];
  const float* sb2   = (const float*)d_in[18];
  const float* sres  = (const float*)d_in[19];
  float* out = (float*)d_out;

  char* ws = (char*)d_ws;
  size_t off = 0;
  auto alloc = [&](size_t bytes)->void*{ void* p = ws + off; off = (off + bytes + 255) & ~(size_t)255; return p; };
  float*          x     = (float*)alloc((size_t)NN*DIM*4);
  float*          y     = (float*)alloc((size_t)NN*DIM*4);
  float*          eo    = (float*)alloc((size_t)2*NASSIGN*DIM*4);
  unsigned short* tokb  = (unsigned short*)alloc((size_t)NN*DIM*2);
  uint8_t*        tokc  = (uint8_t*)alloc((size_t)NASSIGN*DIM);
  unsigned short* g1    = (unsigned short*)alloc((size_t)NN*DIM*2);
  uint8_t*        w1t   = (uint8_t*)alloc((size_t)NE*H2X*DIM);
  uint8_t*        w2t   = (uint8_t*)alloc((size_t)NE*H2X*INNER);
  uint8_t*        w3t   = (uint8_t*)alloc((size_t)NE*DIM*INNER);
  unsigned short* rw1t  = (unsigned short*)alloc((size_t)DIM*DIM*2);
  uint8_t*        h1    = (uint8_t*)alloc((size_t)NASSIGN*INNER);
  uint8_t*        h2b   = (uint8_t*)alloc((size_t)NASSIGN*INNER);
  int*            ridx  = (int*)alloc((size_t)NASSIGN*4);
  float*          rwt   = (float*)alloc((size_t)NASSIGN*4);
  int*            inv   = (int*)alloc((size_t)NASSIGN*4);
  int*            cnt   = (int*)alloc(128);
  int*            cnt2  = cnt + 8;
  float*          pooled= (float*)alloc((size_t)NB*DIM*4);

  tr_all_kernel<<<TR_N1+TR_N2+TR_N3+TR_N4, dim3(32,8), 0, stream>>>(
      we1, w1t, we2, w2t, we3, w3t, rw1, rw1t);
  convln_kernel<<<dim3(NT/CTT, NB), 384, 0, stream>>>(
      res, ln_g, ln_b, conv_w, conv_b, x, tokb, y);
  router_g1_kernel<<<dim3(DIM/128, NN/128), 256, 0, stream>>>(tokb, rw1t, rb1, g1, cnt);
  router2_kernel<<<NN/4, 256, 0, stream>>>(g1, rw2, rb2, ridx, rwt, cnt);
  fillcompact_kernel<<<NASSIGN/256, 256, 0, stream>>>(ridx, cnt, cnt2, inv, tokb, tokc, pooled);

  gemm_sg1_kernel<<<dim3(INNER/128, NN/128, NE), 256, 0, stream>>>(tokc, w1t, be1, cnt, h1);
  gemm_sg2_kernel<<<dim3(INNER/128, NN/128, NE), 256, 0, stream>>>(h1, w2t, be2, cnt, h2b);
  gemm_out_kernel<<<dim3(6, NN/128, NE), 256, 0, stream>>>(h2b, w3t, be3, cnt, eo);
  combine_pooled_kernel<<<dim3(NT/8, NB), 384, 0, stream>>>(
      eo, inv, rwt, x, sres, y, pooled);
  gatefinal_kernel<<<dim3(NT/8, NB), 384, 0, stream>>>(
      pooled, sw1, sb1, sw2, sb2, res, y, out);
}